// Round 12
// baseline (341.510 us; speedup 1.0000x reference)
//
#include <hip/hip_runtime.h>
#include <hip/hip_bf16.h>
#include <math.h>

typedef __hip_bfloat16 bf16;

#define D_MODEL 512
#define NUM_HEADS 8
#define HEAD_DIM 64
#define SEQ_LEN 4096
#define BATCH 2
#define D_FF 2048
#define TOKENS (BATCH * SEQ_LEN)
#define QKV_STRIDE 1536
#define KSPLIT 2

typedef short short4v __attribute__((ext_vector_type(4)));
typedef short short8v __attribute__((ext_vector_type(8)));
typedef float float4v __attribute__((ext_vector_type(4)));
typedef float float2v __attribute__((ext_vector_type(2)));

union frag_u { short8v v8; short4v v4[2]; short s[8]; };
union pack_u { unsigned u[2]; short4v v4; };

__device__ __forceinline__ float b2f(bf16 v) { return __bfloat162float(v); }
__device__ __forceinline__ bf16 f2b(float v) { return __float2bfloat16(v); }
__device__ __forceinline__ short f2bs(float v) { bf16 t = __float2bfloat16(v); return *(short*)&t; }
__device__ __forceinline__ float exp2fast(float x) { return __builtin_amdgcn_exp2f(x); }

// pack two f32 -> (bf16(hi)<<16)|bf16(lo), round-to-nearest via +0x8000 + v_perm
__device__ __forceinline__ unsigned pack_bf16(float lo, float hi) {
    unsigned a = __float_as_uint(hi) + 0x8000u;
    unsigned b = __float_as_uint(lo) + 0x8000u;
    return __builtin_amdgcn_perm(a, b, 0x07060302u);
}

// T12 primitive: single-instruction pack (RNE). No builtin on gfx950 -> asm.
__device__ __forceinline__ unsigned cvt_pk_bf16(float lo, float hi) {
    unsigned r;
    asm("v_cvt_pk_bf16_f32 %0, %1, %2" : "=v"(r) : "v"(lo), "v"(hi));
    return r;
}

// T1: bijective XCD-aware block swizzle (requires nwg % 8 == 0; all our grids are).
__device__ __forceinline__ int3 swz_xyz() {
    int gx = gridDim.x, gy = gridDim.y;
    int id = blockIdx.x + gx * (blockIdx.y + gy * blockIdx.z);
    int nwg = gx * gy * (int)gridDim.z;
    int nid = (id & 7) * (nwg >> 3) + (id >> 3);
    int3 r;
    r.x = nid % gx;
    int t = nid / gx;
    r.y = t % gy;
    r.z = t / gy;
    return r;
}

#define AS1(p) ((__attribute__((address_space(1))) void*)(p))
#define AS3(p) ((__attribute__((address_space(3))) void*)(p))

// Self-detection: 1 if fp32 inputs, 0 if bf16. All lanes sample words 0..63 of x
// (identical ballot in every wave -> deterministic, no sync needed).
__device__ __forceinline__ int self_detect(const unsigned* __restrict__ xw, int tid) {
    unsigned w = xw[tid & 63];
    unsigned e = (w >> 7) & 0xFFu;
    unsigned long long b = __ballot(e >= 110 && e <= 140);
    return __popcll(b) < 32;
}

// ---------------- fused weight prep + LN1 (one kernel, R11) -------------------
__device__ __forceinline__ void do_tr(const void* __restrict__ src, bf16* __restrict__ dst,
                                      int K, int N, int n0, int k0, int fl, int tid,
                                      bf16 (*tile)[65]) {
    int c = tid & 63, r4 = tid >> 6;
#pragma unroll
    for (int t = 0; t < 16; t++) {
        int r = t * 4 + r4;
        size_t si = (size_t)(k0 + r) * N + n0 + c;
        float v = fl ? ((const float*)src)[si] : b2f(((const bf16*)src)[si]);
        tile[r][c] = f2b(v);
    }
    __syncthreads();
#pragma unroll
    for (int t = 0; t < 16; t++) {
        int r = t * 4 + r4;
        dst[(size_t)(n0 + r) * K + k0 + c] = tile[c][r];
    }
}

__global__ void prep_ln_kernel(const void* x, const void* Wq, const void* Wk, const void* Wv,
                               const void* Wo, const void* W1, const void* W2,
                               const void* bq, const void* bk, const void* bv, const void* bo,
                               const void* b1, const void* b2,
                               const void* g1, const void* e1, const void* g2, const void* e2,
                               bf16* __restrict__ Wqkvt /* + Wot contiguous */,
                               bf16* __restrict__ W1t, bf16* __restrict__ W2t,
                               bf16* __restrict__ small, int* __restrict__ flag,
                               bf16* __restrict__ hb) {
    __shared__ bf16 tile[64][65];
    __shared__ float rs[4], rss[4], stat[2];
    int blk = blockIdx.x, tid = threadIdx.x;
    int fl = self_detect((const unsigned*)x, tid);
    if (blk == 0 && tid == 0) flag[0] = fl;   // publish for downstream kernels
    if (blk < 256) {                       // Wq|Wk|Wv|Wo 512x512
        int z = blk >> 6, tt = blk & 63;
        const void* src = (z == 0) ? Wq : (z == 1) ? Wk : (z == 2) ? Wv : Wo;
        do_tr(src, Wqkvt + (size_t)z * 512 * 512, 512, 512, (tt & 7) * 64, (tt >> 3) * 64,
              fl, tid, tile);
    } else if (blk < 512) {                // W1: [512][2048] -> [2048][512]
        int tt = blk - 256;
        do_tr(W1, W1t, 512, 2048, (tt & 31) * 64, (tt >> 5) * 64, fl, tid, tile);
    } else if (blk < 768) {                // W2: [2048][512] -> [512][2048]
        int tt = blk - 512;
        do_tr(W2, W2t, 2048, 512, (tt & 7) * 64, (tt >> 3) * 64, fl, tid, tile);
    } else if (blk < 794) {                // small vectors
        int i = (blk - 768) * 256 + tid;   // 0..6655
        const void* src; int off;
        if (i < 512)       { src = bq; off = 0; }
        else if (i < 1024) { src = bk; off = 512; }
        else if (i < 1536) { src = bv; off = 1024; }
        else if (i < 2048) { src = bo; off = 1536; }
        else if (i < 4096) { src = b1; off = 2048; }
        else if (i < 4608) { src = b2; off = 4096; }
        else if (i < 5120) { src = g1; off = 4608; }
        else if (i < 5632) { src = e1; off = 5120; }
        else if (i < 6144) { src = g2; off = 5632; }
        else               { src = e2; off = 6144; }
        int j = i - off;
        small[i] = fl ? f2b(((const float*)src)[j]) : ((const bf16*)src)[j];
    } else {                               // LN1 for token (blk-794), raw g/b
        int t = blk - 794;
        float v0, v1, gg0, gg1, bb0, bb1;
        if (fl) {
            const float* xr = (const float*)x + (size_t)t * D_MODEL;
            v0 = xr[tid]; v1 = xr[tid + 256];
            gg0 = ((const float*)g1)[tid]; gg1 = ((const float*)g1)[tid + 256];
            bb0 = ((const float*)e1)[tid]; bb1 = ((const float*)e1)[tid + 256];
        } else {
            const bf16* xr = (const bf16*)x + (size_t)t * D_MODEL;
            v0 = b2f(xr[tid]); v1 = b2f(xr[tid + 256]);
            gg0 = b2f(((const bf16*)g1)[tid]); gg1 = b2f(((const bf16*)g1)[tid + 256]);
            bb0 = b2f(((const bf16*)e1)[tid]); bb1 = b2f(((const bf16*)e1)[tid + 256]);
        }
        float s = v0 + v1, ss = v0 * v0 + v1 * v1;
        for (int o = 32; o > 0; o >>= 1) {
            s += __shfl_down(s, o);
            ss += __shfl_down(ss, o);
        }
        int w = tid >> 6, l = tid & 63;
        if (l == 0) { rs[w] = s; rss[w] = ss; }
        __syncthreads();
        if (tid == 0) {
            float S = rs[0] + rs[1] + rs[2] + rs[3];
            float SS = rss[0] + rss[1] + rss[2] + rss[3];
            float mu = S / (float)D_MODEL;
            float var = SS / (float)D_MODEL - mu * mu;
            stat[0] = mu;
            stat[1] = rsqrtf(var + 1e-5f);
        }
        __syncthreads();
        float mu = stat[0], rstd = stat[1];
        bf16* orow = hb + (size_t)t * D_MODEL;
        orow[tid]       = f2b((v0 - mu) * rstd * gg0 + bb0);
        orow[tid + 256] = f2b((v1 - mu) * rstd * gg1 + bb1);
    }
}

// ---------------- LayerNorm (LN2 only): one block per token -------------------
template <int MODE>
__global__ void ln_kernel(const void* __restrict__ xv, const bf16* __restrict__ g,
                          const bf16* __restrict__ b, bf16* __restrict__ out,
                          const int* __restrict__ flag) {
    int t = blockIdx.x;
    int tid = threadIdx.x;
    int fl = (MODE == 2) ? *flag : 0;
    float v0, v1;
    if (fl) {
        const float* xr = (const float*)xv + (size_t)t * D_MODEL;
        v0 = xr[tid]; v1 = xr[tid + 256];
    } else {
        const bf16* xr = (const bf16*)xv + (size_t)t * D_MODEL;
        v0 = b2f(xr[tid]); v1 = b2f(xr[tid + 256]);
    }
    float s = v0 + v1, ss = v0 * v0 + v1 * v1;
    for (int o = 32; o > 0; o >>= 1) {
        s += __shfl_down(s, o);
        ss += __shfl_down(ss, o);
    }
    __shared__ float rs[4], rss[4], stat[2];
    int w = tid >> 6, l = tid & 63;
    if (l == 0) { rs[w] = s; rss[w] = ss; }
    __syncthreads();
    if (tid == 0) {
        float S = rs[0] + rs[1] + rs[2] + rs[3];
        float SS = rss[0] + rss[1] + rss[2] + rss[3];
        float mu = S / (float)D_MODEL;
        float var = SS / (float)D_MODEL - mu * mu;
        stat[0] = mu;
        stat[1] = rsqrtf(var + 1e-5f);
    }
    __syncthreads();
    float mu = stat[0], rstd = stat[1];
    bf16* orow = out + (size_t)t * D_MODEL;
    orow[tid]       = f2b((v0 - mu) * rstd * b2f(g[tid])       + b2f(b[tid]));
    orow[tid + 256] = f2b((v1 - mu) * rstd * b2f(g[tid + 256]) + b2f(b[tid + 256]));
}

__device__ __forceinline__ float gelu_tanh(float v) {
    float u = 0.7978845608f * (v + 0.044715f * v * v * v);
    float e2 = __expf(-2.f * u);
    return v / (1.f + e2);
}

// ---------------- MFMA GEMM 128x64, BK=32 double-buffered 2-phase -------------
// QKV (VT=1: V-part transposed to Vt_out), FFN1 (ACT=1), FFN2, fallback O-proj.
template <int ACT, int RES, int OUTMODE, int VT>
__global__ __launch_bounds__(256) void mfma_gemm64(
    const bf16* __restrict__ A, const bf16* __restrict__ Wt,
    const bf16* __restrict__ bias, const void* __restrict__ res,
    void* __restrict__ Cout, bf16* __restrict__ Vt_out,
    const int* __restrict__ flag, int M, int N, int K) {
    __shared__ bf16 As[2][128 * 32];
    __shared__ bf16 Bs[2][64 * 32];
    int tid = threadIdx.x, wave = tid >> 6, lane = tid & 63;
    int m = lane & 15, g = lane >> 4;
    int3 sw = swz_xyz();
    int row0 = sw.y * 128, col0 = sw.x * 64;
    int R0 = wave * 32;
    int fl = (OUTMODE == 2 || RES == 3) ? *flag : 0;
    float4v acc[2][4] = {};

    int srow = lane >> 2;            // 0..15
    int scol = (lane & 3) * 8;       // bf16 col 0/8/16/24
    const bf16* Ab = A  + (size_t)(row0 + wave * 32 + srow) * K + scol;
    const bf16* Bb = Wt + (size_t)(col0 + wave * 16 + srow) * K + scol;   // 16 rows/wave

#define GSTAGE64(buf, kk0)                                                         \
    {                                                                              \
        _Pragma("unroll")                                                          \
        for (int t = 0; t < 2; t++)                                                \
            __builtin_amdgcn_global_load_lds(AS1(Ab + (size_t)(t * 16) * K + (kk0)),\
                AS3(&As[buf][(wave * 32 + t * 16) * 32]), 16, 0, 0);               \
        __builtin_amdgcn_global_load_lds(AS1(Bb + (kk0)),                          \
            AS3(&Bs[buf][(wave * 16) * 32]), 16, 0, 0);                            \
    }

    int nk = K >> 5;
    GSTAGE64(0, 0);
    __syncthreads();
    for (int it = 0; it < nk; it++) {
        int cur = it & 1;
        if (it + 1 < nk) GSTAGE64(cur ^ 1, (it + 1) * 32);
        short8v fa[2], fb[4];
#pragma unroll
        for (int i = 0; i < 2; i++)
            fa[i] = *(const short8v*)&As[cur][(R0 + i * 16 + m) * 32 + g * 8];
#pragma unroll
        for (int j = 0; j < 4; j++)
            fb[j] = *(const short8v*)&Bs[cur][(j * 16 + m) * 32 + g * 8];
        __builtin_amdgcn_s_setprio(1);
#pragma unroll
        for (int i = 0; i < 2; i++)
#pragma unroll
            for (int j = 0; j < 4; j++)
                acc[i][j] = __builtin_amdgcn_mfma_f32_16x16x32_bf16(fa[i], fb[j], acc[i][j], 0, 0, 0);
        __builtin_amdgcn_s_setprio(0);
        __syncthreads();
    }
#undef GSTAGE64

    if (VT && col0 >= 1024) {
        // V-part of QKV: write transposed into Vt_g [bh][64][SEQ_LEN].
#pragma unroll
        for (int i = 0; i < 2; i++) {
            int row = row0 + R0 + i * 16 + g * 4;
            int b = row >> 12, s = row & (SEQ_LEN - 1);
#pragma unroll
            for (int j = 0; j < 4; j++) {
                int col = col0 + j * 16 + m;
                int hh = (col - 1024) >> 6, d = col & 63;
                float bi = b2f(bias[col]);
                pack_u oo;
                oo.u[0] = pack_bf16(acc[i][j][0] + bi, acc[i][j][1] + bi);
                oo.u[1] = pack_bf16(acc[i][j][2] + bi, acc[i][j][3] + bi);
                *(short4v*)&Vt_out[((size_t)((b << 3) + hh) * 64 + d) * SEQ_LEN + s] = oo.v4;
            }
        }
        return;
    }

#pragma unroll
    for (int i = 0; i < 2; i++) {
#pragma unroll
        for (int r = 0; r < 4; r++) {
            int row = row0 + R0 + i * 16 + g * 4 + r;
#pragma unroll
            for (int j = 0; j < 4; j++) {
                int col = col0 + j * 16 + m;
                float v = acc[i][j][r] + b2f(bias[col]);
                if (ACT == 1) v = gelu_tanh(v);
                size_t idx = (size_t)row * N + col;
                if (RES == 2) v += b2f(((const bf16*)res)[idx]);
                if (RES == 3) v += fl ? ((const float*)res)[idx]
                                      : b2f(((const bf16*)res)[idx]);
                if (OUTMODE == 0) ((bf16*)Cout)[idx] = f2b(v);
                else {
                    if (fl) ((float*)Cout)[idx] = v;
                    else ((bf16*)Cout)[idx] = f2b(v);
                }
            }
        }
    }
}

// ---------------- O-projection with FUSED attn-merge A-staging (R12) ----------
// A-operand = merge(Op partial 0, Op partial 1) computed in registers during
// staging (T14 issue-early / write-late), ds_written into a pad-40 As (free of
// the gload_lds linear constraint -> ~2-way banks instead of 8-16). Deletes the
// attn_merge kernel + the ab round-trip (~50 MB).
__global__ __launch_bounds__(256) void oproj_merge(
    const bf16* __restrict__ Op, const float2* __restrict__ ml,
    const bf16* __restrict__ Wt, const bf16* __restrict__ bias,
    const void* __restrict__ res, bf16* __restrict__ Cout,
    const int* __restrict__ flag) {
    const int N = D_MODEL, K = D_MODEL;
    __shared__ bf16 As[2][128 * 40];     // pad 32->40 (80B rows, 16B aligned)
    __shared__ bf16 Bs[2][64 * 32];
    int tid = threadIdx.x, wave = tid >> 6, lane = tid & 63;
    int m = lane & 15, g = lane >> 4;
    int3 sw = swz_xyz();
    int row0 = sw.y * 128, col0 = sw.x * 64;
    int R0 = wave * 32;
    int fl = *flag;
    float4v acc[2][4] = {};

    // B staging (gload_lds, same as gemm64)
    int srow = lane >> 2, scol = (lane & 3) * 8;
    const bf16* Bb = Wt + (size_t)(col0 + wave * 16 + srow) * K + scol;

    // A merge-staging: thread -> (tile row r, col half ch); 16 cols/thread.
    int r = tid >> 1, ch = tid & 1;
    int rg = row0 + r;
    int bb = rg >> 12, s = rg & (SEQ_LEN - 1);

    short8v a00, a01, a10, a11;          // partial0 lo/hi, partial1 lo/hi
    float2 m0v, m1v;

#define ALOAD(kk)                                                              \
    {                                                                          \
        int h = (kk) >> 6, dbase = ((kk) & 63) + ch * 16;                      \
        int bh = bb * 8 + h;                                                   \
        const unsigned short* p0 = (const unsigned short*)Op +                 \
            ((size_t)bh * SEQ_LEN + s) * 64 + dbase;                           \
        const unsigned short* p1 = (const unsigned short*)Op +                 \
            ((size_t)(16 + bh) * SEQ_LEN + s) * 64 + dbase;                    \
        a00 = *(const short8v*)(p0);  a01 = *(const short8v*)(p0 + 8);         \
        a10 = *(const short8v*)(p1);  a11 = *(const short8v*)(p1 + 8);         \
        m0v = ml[(size_t)bh * SEQ_LEN + s];                                    \
        m1v = ml[(size_t)(16 + bh) * SEQ_LEN + s];                             \
    }

#define AMERGE_WRITE(buf)                                                      \
    {                                                                          \
        float Mx = fmaxf(m0v.x, m1v.x);                                        \
        float w0 = exp2fast(m0v.x - Mx), w1 = exp2fast(m1v.x - Mx);            \
        float inv = 1.f / (m0v.y * w0 + m1v.y * w1);                           \
        w0 *= inv; w1 *= inv;                                                  \
        frag_u u0, u1, v0, v1, o0, o1;                                         \
        u0.v8 = a00; u1.v8 = a01; v0.v8 = a10; v1.v8 = a11;                    \
        _Pragma("unroll")                                                      \
        for (int j = 0; j < 8; j++) {                                          \
            o0.s[j] = f2bs(b2f(*(bf16*)&u0.s[j]) * w0 + b2f(*(bf16*)&v0.s[j]) * w1); \
            o1.s[j] = f2bs(b2f(*(bf16*)&u1.s[j]) * w0 + b2f(*(bf16*)&v1.s[j]) * w1); \
        }                                                                      \
        *(short8v*)&As[buf][r * 40 + ch * 16]     = o0.v8;                     \
        *(short8v*)&As[buf][r * 40 + ch * 16 + 8] = o1.v8;                     \
    }

#define BSTAGE(buf, kk0)                                                       \
    __builtin_amdgcn_global_load_lds(AS1(Bb + (kk0)),                          \
        AS3(&Bs[buf][(wave * 16) * 32]), 16, 0, 0);

    int nk = K >> 5;   // 16
    ALOAD(0);
    BSTAGE(0, 0);
    AMERGE_WRITE(0);
    __syncthreads();
    for (int it = 0; it < nk; it++) {
        int cur = it & 1;
        if (it + 1 < nk) { ALOAD((it + 1) * 32); BSTAGE(cur ^ 1, (it + 1) * 32); }
        short8v fa[2], fb[4];
#pragma unroll
        for (int i = 0; i < 2; i++)
            fa[i] = *(const short8v*)&As[cur][(R0 + i * 16 + m) * 40 + g * 8];
#pragma unroll
        for (int j = 0; j < 4; j++)
            fb[j] = *(const short8v*)&Bs[cur][(j * 16 + m) * 32 + g * 8];
        __builtin_amdgcn_s_setprio(1);
#pragma unroll
        for (int i = 0; i < 2; i++)
#pragma unroll
            for (int j = 0; j < 4; j++)
                acc[i][j] = __builtin_amdgcn_mfma_f32_16x16x32_bf16(fa[i], fb[j], acc[i][j], 0, 0, 0);
        __builtin_amdgcn_s_setprio(0);
        __syncthreads();   // all reads of buf cur done; drains A/B loads of t+1
        if (it + 1 < nk) AMERGE_WRITE(cur ^ 1);
        __syncthreads();   // A(t+1) visible before next iter's ds_reads
    }
#undef ALOAD
#undef AMERGE_WRITE
#undef BSTAGE

    // epilogue: bias + residual(raw x) -> x1 (bf16)
#pragma unroll
    for (int i = 0; i < 2; i++) {
#pragma unroll
        for (int rr = 0; rr < 4; rr++) {
            int row = row0 + R0 + i * 16 + g * 4 + rr;
#pragma unroll
            for (int j = 0; j < 4; j++) {
                int col = col0 + j * 16 + m;
                float v = acc[i][j][rr] + b2f(bias[col]);
                size_t idx = (size_t)row * N + col;
                v += fl ? ((const float*)res)[idx] : b2f(((const bf16*)res)[idx]);
                Cout[idx] = f2b(v);
            }
        }
    }
}

// ---------------- Flash attention, S^T formulation, 32q/wave, split-K=KS ------
// Unchanged (plateaued ~110us: VALU near algorithmic floor, register-capped).
#define F3(a, b, c) fmaxf(fmaxf((a), (b)), (c))
template <int KS>
__global__ __launch_bounds__(256, 4) void flash_attn(const bf16* __restrict__ Q,
                                                     const bf16* __restrict__ K,
                                                     const bf16* __restrict__ Vt_g,
                                                     bf16* __restrict__ Op,
                                                     float2* __restrict__ mlout) {
    __shared__ bf16 Ks[64][72];      // overlaid by per-wave Pt[16][72] after barrier A
    __shared__ bf16 Vt[64][72];

    int tid = threadIdx.x;
    int wave = tid >> 6, lane = tid & 63;
    int m = lane & 15, g = lane >> 4;
    bf16* PtW = &Ks[0][0] + wave * (16 * 72);   // wave-exclusive 2304B overlay

    int3 sw = swz_xyz();
    int bh = sw.y;
    size_t base = (size_t)(bh >> 3) * SEQ_LEN * QKV_STRIDE + (size_t)(bh & 7) * HEAD_DIM;
    int q0w = sw.x * 128 + wave * 32;

    const float qscale = 0.125f * 1.44269504f;   // fold log2(e) -> exp2 softmax
    short8v aQ[2][2];
#pragma unroll
    for (int mt = 0; mt < 2; mt++) {
        const bf16* qp = Q + base + (size_t)(q0w + mt * 16 + m) * QKV_STRIDE + g * 8;
#pragma unroll
        for (int c = 0; c < 2; c++) {
            frag_u u;
#pragma unroll
            for (int j = 0; j < 8; j++) u.s[j] = f2bs(b2f(qp[c * 32 + j]) * qscale);
            aQ[mt][c] = u.v8;
        }
    }

    float mrow[2] = {-1e30f, -1e30f};
    float lrow[2] = {0.f, 0.f};
    float4v oacc[2][4] = {};

    int sk = tid >> 2, sd = (tid & 3) * 16;
    int vrow = tid >> 2, vcol = (tid & 3) * 16;

    const unsigned short* Ku = (const unsigned short*)(K + base);
    const unsigned short* Vg = (const unsigned short*)Vt_g +
                               (size_t)bh * 64 * SEQ_LEN + (size_t)vrow * SEQ_LEN;

    int t0 = sw.z * (64 / KS);
    int t1 = t0 + 64 / KS;

    // staging registers (single-buffered: load t+1 -> compute t -> store t+1)
    short8v rk0, rk1, rv0, rv1;
    {   // prologue: tile t0 global -> regs -> LDS
        int kt0 = t0 * 64;
        const unsigned short* kp = Ku + (size_t)(kt0 + sk) * QKV_STRIDE + sd;
        rk0 = *(const short8v*)(kp);
        rk1 = *(const short8v*)(kp + 8);
        rv0 = *(const short8v*)(Vg + kt0 + vcol);
        rv1 = *(const short8v*)(Vg + kt0 + vcol + 8);
        *(short8v*)&Ks[sk][sd]     = rk0;
        *(short8v*)&Ks[sk][sd + 8] = rk1;
        *(short8v*)&Vt[vrow][vcol]     = rv0;
        *(short8v*)&Vt[vrow][vcol + 8] = rv1;
    }
    __syncthreads();

    for (int t = t0; t < t1; t++) {
        // T14 issue-early: next tile's global loads go in flight NOW.
        if (t + 1 < t1) {
            int ktn = (t + 1) * 64;
            const unsigned short* kp = Ku + (size_t)(ktn + sk) * QKV_STRIDE + sd;
            rk0 = *(const short8v*)(kp);
            rk1 = *(const short8v*)(kp + 8);
            rv0 = *(const short8v*)(Vg + ktn + vcol);
            rv1 = *(const short8v*)(Vg + ktn + vcol + 8);
        }

        // QK^T: per kt load K frags once, use for both m-tiles
        float4v st[2][4];
        __builtin_amdgcn_s_setprio(1);
#pragma unroll
        for (int kt = 0; kt < 4; kt++) {
            short8v bK0 = *(const short8v*)&Ks[kt * 16 + m][g * 8];
            short8v bK1 = *(const short8v*)&Ks[kt * 16 + m][32 + g * 8];
#pragma unroll
            for (int mt = 0; mt < 2; mt++) {
                float4v a = {0.f, 0.f, 0.f, 0.f};
                a = __builtin_amdgcn_mfma_f32_16x16x32_bf16(bK0, aQ[mt][0], a, 0, 0, 0);
                a = __builtin_amdgcn_mfma_f32_16x16x32_bf16(bK1, aQ[mt][1], a, 0, 0, 0);
                st[mt][kt] = a;
            }
        }
        __builtin_amdgcn_s_setprio(0);

        __syncthreads();   // barrier A: ALL waves' Ks reads done -> Pt may overlay

        // online softmax per m-tile (exp2 domain, defer-max); Pt in Ks overlay
        short8v bP[2][2];
#pragma unroll
        for (int mt = 0; mt < 2; mt++) {
            float u0 = F3(st[mt][0][0], st[mt][0][1], st[mt][0][2]);
            float u1 = F3(st[mt][0][3], st[mt][1][0], st[mt][1][1]);
            float u2 = F3(st[mt][1][2], st[mt][1][3], st[mt][2][0]);
            float u3 = F3(st[mt][2][1], st[mt][2][2], st[mt][2][3]);
            float u4 = F3(st[mt][3][0], st[mt][3][1], st[mt][3][2]);
            float tm = fmaxf(F3(u0, u1, u2), F3(u3, u4, st[mt][3][3]));
            tm = fmaxf(tm, __shfl_xor(tm, 16));
            tm = fmaxf(tm, __shfl_xor(tm, 32));
            // T13 defer-max: only rescale when the max grew by > 8 (exp2 dom).
            if (!__all(tm - mrow[mt] <= 8.f)) {
                float mnew = fmaxf(mrow[mt], tm);
                float alpha = exp2fast(mrow[mt] - mnew);
                mrow[mt] = mnew;
                lrow[mt] *= alpha;
#pragma unroll
                for (int dt = 0; dt < 4; dt++)
#pragma unroll
                    for (int r = 0; r < 4; r++) oacc[mt][dt][r] *= alpha;
            }
            float mcur = mrow[mt];
            float2v ps = {0.f, 0.f};
#pragma unroll
            for (int kt = 0; kt < 4; kt++) {
                float p0 = exp2fast(st[mt][kt][0] - mcur);
                float p1 = exp2fast(st[mt][kt][1] - mcur);
                float p2 = exp2fast(st[mt][kt][2] - mcur);
                float p3 = exp2fast(st[mt][kt][3] - mcur);
                float2v a = {p0, p1}, b = {p2, p3};
                ps += a + b;                       // v_pk_add_f32
                pack_u pp;
                pp.u[0] = cvt_pk_bf16(p0, p1);
                pp.u[1] = cvt_pk_bf16(p2, p3);
                *(short4v*)&PtW[m * 72 + kt * 16 + g * 4] = pp.v4;
            }
            lrow[mt] += ps[0] + ps[1];
            // read back this mt's P^T frags (same wave; lgkmcnt orders it),
            // then the 16-row region is reused by mt=1.
#pragma unroll
            for (int c = 0; c < 2; c++)
                bP[mt][c] = *(const short8v*)&PtW[m * 72 + c * 32 + g * 8];
        }

        // PV: Vt A-frags loaded once, used for both m-tiles
        __builtin_amdgcn_s_setprio(1);
#pragma unroll
        for (int dt = 0; dt < 4; dt++) {
#pragma unroll
            for (int c = 0; c < 2; c++) {
                short8v av = *(const short8v*)&Vt[dt * 16 + m][c * 32 + g * 8];
#pragma unroll
                for (int mt = 0; mt < 2; mt++)
                    oacc[mt][dt] = __builtin_amdgcn_mfma_f32_16x16x32_bf16(av, bP[mt][c], oacc[mt][dt], 0, 0, 0);
            }
        }
        __builtin_amdgcn_s_setprio(0);

        __syncthreads();   // barrier B: PV Vt reads + all Pt reads done
        // T14 write-late: regs (already landed during compute) -> LDS
        if (t + 1 < t1) {
            *(short8v*)&Ks[sk][sd]     = rk0;   // overwrites the Pt overlay
            *(short8v*)&Ks[sk][sd + 8] = rk1;
            *(short8v*)&Vt[vrow][vcol]     = rv0;
            *(short8v*)&Vt[vrow][vcol + 8] = rv1;
        }
        __syncthreads();   // barrier C: staged tile t+1 visible
    }

    size_t zoff = (size_t)sw.z * NUM_HEADS * BATCH + bh;
    size_t pbase = zoff * (SEQ_LEN * (size_t)HEAD_DIM);
#pragma unroll
    for (int mt = 0; mt < 2; mt++) {
        float l = lrow[mt];
        l += __shfl_xor(l, 16);
        l += __shfl_xor(l, 32);
        int q = q0w + mt * 16 + m;
        bf16* orow = Op + pbase + (size_t)q * HEAD_DIM;
#pragma unroll
        for (int dt = 0; dt < 4; dt++) {
            pack_u oo;
            oo.u[0] = cvt_pk_bf16(oacc[mt][dt][0], oacc[mt][dt][1]);
            oo.u[1] = cvt_pk_bf16(oacc[mt][dt][2], oacc[mt][dt][3]);
            *(short4v*)&orow[dt * 16 + g * 4] = oo.v4;
        }
        if (g == 0) mlout[zoff * SEQ_LEN + q] = make_float2(mrow[mt], l);
    }
}

// Merge KS partials -> attention output ab (fallback path only)
template <int KS>
__global__ void attn_merge(const bf16* __restrict__ Op, const float2* __restrict__ ml,
                           bf16* __restrict__ O) {
    int i = blockIdx.x * 256 + threadIdx.x;   // over 16*4096*64
    int d = i & 63;
    int q = (i >> 6) & (SEQ_LEN - 1);
    int bh = i >> 18;
    const int HQ = NUM_HEADS * BATCH * SEQ_LEN;
    float2 a[KS];
    float M = -1e30f;
#pragma unroll
    for (int p = 0; p < KS; p++) {
        a[p] = ml[(size_t)p * HQ + bh * SEQ_LEN + q];
        M = fmaxf(M, a[p].x);
    }
    float w[KS];
    float denom = 0.f;
#pragma unroll
    for (int p = 0; p < KS; p++) {
        w[p] = exp2fast(a[p].x - M);
        denom += a[p].y * w[p];
    }
    float inv = 1.f / denom;
    const size_t NP = (size_t)HQ * HEAD_DIM;
    float o = 0.f;
#pragma unroll
    for (int p = 0; p < KS; p++) o += b2f(Op[(size_t)p * NP + i]) * w[p];
    o *= inv;
    O[((size_t)((bh >> 3) * SEQ_LEN + q)) * D_MODEL + (bh & 7) * HEAD_DIM + d] = f2b(o);
}

// ------------------------------------------------------------------------------
extern "C" void kernel_launch(void* const* d_in, const int* in_sizes, int n_in,
                              void* d_out, int out_size, void* d_ws, size_t ws_size,
                              hipStream_t stream) {
    const void* x     = d_in[0];
    const void* Wq    = d_in[1];
    const void* bq    = d_in[2];
    const void* Wk    = d_in[3];
    const void* bk    = d_in[4];
    const void* Wv    = d_in[5];
    const void* bv    = d_in[6];
    const void* Wo    = d_in[7];
    const void* bo    = d_in[8];
    const void* ln1_g = d_in[9];
    const void* ln1_b = d_in[10];
    const void* ln2_g = d_in[11];
    const void* ln2_b = d_in[12];
    const void* W1    = d_in[13];
    const void* b1    = d_in[14];
    const void* W2    = d_in[15];
    const void* b2    = d_in[16];

    // ---- workspace layout ----
    char* p = (char*)d_ws;
    int* flag = (int*)p;                      p += 256;
    size_t tok_d = (size_t)TOKENS * D_MODEL;
    // region2: x1b + hb (16.8 MB); also fallback Opart overlay
    char* region2 = p;                        p += 2 * tok_d * 2;
    bf16* x1b   = (bf16*)region2;                              // [TOKENS][512]
    bf16* hb    = (bf16*)(region2 + tok_d * 2);                // [TOKENS][512]
    bf16*  bigA = (bf16*)p;                   p += (size_t)TOKENS * D_FF * 2;  // 33.6 MB
    bf16*  qkvb = bigA;                                   // [TOKENS][1536]
    bf16*  ab   = bigA + (size_t)TOKENS * QKV_STRIDE;     // [TOKENS][512] (fallback)
    bf16*  ffb  = bigA;                                   // [TOKENS][2048]
    bf16*  Wqkvt = (bf16*)p;                  p += (size_t)QKV_STRIDE * D_MODEL * 2;
    bf16*  Wot   = (bf16*)p;                  p += (size_t)D_MODEL * D_MODEL * 2;  // contiguous
    bf16*  W1t   = (bf16*)p;                  p += (size_t)D_FF * D_MODEL * 2;
    bf16*  W2t   = (bf16*)p;                  p += (size_t)D_MODEL * D_FF * 2;
    bf16*  Vtg   = (bf16*)p;                  p += (size_t)NUM_HEADS * BATCH * HEAD_DIM * SEQ_LEN * 2;
    float2* mlb  = (float2*)p;                p += (size_t)KSPLIT * NUM_HEADS * BATCH * SEQ_LEN * sizeof(float2);
    bf16*  small = (bf16*)p;                  p += 6656 * 2;
    // R12: Op partials at the tail (disjoint from x1b!) so oproj_merge can read
    // them while writing x1b. Capacity proven by R5/R6's tail usage.
    bf16* Optail = (bf16*)p;
    size_t opbytes = (size_t)KSPLIT * NUM_HEADS * BATCH * SEQ_LEN * HEAD_DIM * 2;  // 33.6 MB
    int fused = ((char*)Optail + opbytes - (char*)d_ws) <= (ptrdiff_t)ws_size;
    bf16* Opart = fused ? Optail : (bf16*)region2;

    bf16* bias_qkv = small + 0;
    bf16* bias_o   = small + 1536;
    bf16* b1b      = small + 2048;
    bf16* b2b      = small + 4096;
    bf16* g1b      = small + 4608;
    bf16* be1b     = small + 5120;
    bf16* g2b      = small + 5632;
    bf16* be2b     = small + 6144;
    (void)g1b; (void)be1b;

    // fused prep + LN1 (LN1 reads raw x and raw ln1_g/ln1_b; flag via self_detect)
    prep_ln_kernel<<<794 + TOKENS, 256, 0, stream>>>(
        x, Wq, Wk, Wv, Wo, W1, W2, bq, bk, bv, bo, b1, b2,
        ln1_g, ln1_b, ln2_g, ln2_b, Wqkvt, W1t, W2t, small, flag, hb);

    // fused QKV projection (64-col tiles, 1536 blocks = 6/CU);
    // V part written transposed straight into Vtg
    mfma_gemm64<0, 0, 0, 1><<<dim3(QKV_STRIDE / 64, TOKENS / 128), 256, 0, stream>>>(
        hb, Wqkvt, bias_qkv, nullptr, qkvb, Vtg, flag, TOKENS, QKV_STRIDE, D_MODEL);

    flash_attn<KSPLIT><<<dim3(SEQ_LEN / 128, 16, KSPLIT), 256, 0, stream>>>(
        qkvb, qkvb + 512, Vtg, Opart, mlb);

    if (fused) {
        // O projection with fused attn-merge A-staging + residual(raw x) -> x1
        oproj_merge<<<dim3(D_MODEL / 64, TOKENS / 128), 256, 0, stream>>>(
            Opart, mlb, Wot, bias_o, x, x1b, flag);
    } else {
        attn_merge<KSPLIT><<<(NUM_HEADS * BATCH * SEQ_LEN * HEAD_DIM) / 256, 256, 0, stream>>>(
            Opart, mlb, ab);
        mfma_gemm64<0, 3, 0, 0><<<dim3(D_MODEL / 64, TOKENS / 128), 256, 0, stream>>>(
            ab, Wot, bias_o, x, x1b, nullptr, flag, TOKENS, D_MODEL, D_MODEL);
    }

    ln_kernel<0><<<TOKENS, 256, 0, stream>>>(x1b, g2b, be2b, hb, flag);

    // FFN1 + GELU (64-col tiles, 2048 blocks = 6/CU)
    mfma_gemm64<1, 0, 0, 0><<<dim3(D_FF / 64, TOKENS / 128), 256, 0, stream>>>(
        hb, W1t, b1b, nullptr, ffb, nullptr, flag, TOKENS, D_FF, D_MODEL);

    // FFN2 + residual(x1 bf16) -> out (dtype per flag); 512 blocks
    mfma_gemm64<0, 2, 2, 0><<<dim3(D_MODEL / 64, TOKENS / 128), 256, 0, stream>>>(
        ffb, W2t, b2b, x1b, d_out, nullptr, flag, TOKENS, D_MODEL, D_FF);
}

// Round 13
// 340.765 us; speedup vs baseline: 1.0022x; 1.0022x over previous
//
#include <hip/hip_runtime.h>
#include <hip/hip_bf16.h>
#include <math.h>

typedef __hip_bfloat16 bf16;

#define D_MODEL 512
#define NUM_HEADS 8
#define HEAD_DIM 64
#define SEQ_LEN 4096
#define BATCH 2
#define D_FF 2048
#define TOKENS (BATCH * SEQ_LEN)
#define QKV_STRIDE 1536
#define KSPLIT 2

typedef short short4v __attribute__((ext_vector_type(4)));
typedef short short8v __attribute__((ext_vector_type(8)));
typedef float float4v __attribute__((ext_vector_type(4)));
typedef float float2v __attribute__((ext_vector_type(2)));

union frag_u { short8v v8; short4v v4[2]; short s[8]; };
union pack_u { unsigned u[2]; short4v v4; };
union pack8_u { unsigned u[4]; short8v v8; };

__device__ __forceinline__ float b2f(bf16 v) { return __bfloat162float(v); }
__device__ __forceinline__ bf16 f2b(float v) { return __float2bfloat16(v); }
__device__ __forceinline__ short f2bs(float v) { bf16 t = __float2bfloat16(v); return *(short*)&t; }
__device__ __forceinline__ float exp2fast(float x) { return __builtin_amdgcn_exp2f(x); }
__device__ __forceinline__ float bs2f(short s) { bf16 t = *(bf16*)&s; return __bfloat162float(t); }

// pack two f32 -> (bf16(hi)<<16)|bf16(lo), round-to-nearest via +0x8000 + v_perm
__device__ __forceinline__ unsigned pack_bf16(float lo, float hi) {
    unsigned a = __float_as_uint(hi) + 0x8000u;
    unsigned b = __float_as_uint(lo) + 0x8000u;
    return __builtin_amdgcn_perm(a, b, 0x07060302u);
}

// T12 primitive: single-instruction pack (RNE). No builtin on gfx950 -> asm.
__device__ __forceinline__ unsigned cvt_pk_bf16(float lo, float hi) {
    unsigned r;
    asm("v_cvt_pk_bf16_f32 %0, %1, %2" : "=v"(r) : "v"(lo), "v"(hi));
    return r;
}

// T1: bijective XCD-aware block swizzle (requires nwg % 8 == 0; all our grids are).
__device__ __forceinline__ int3 swz_xyz() {
    int gx = gridDim.x, gy = gridDim.y;
    int id = blockIdx.x + gx * (blockIdx.y + gy * blockIdx.z);
    int nwg = gx * gy * (int)gridDim.z;
    int nid = (id & 7) * (nwg >> 3) + (id >> 3);
    int3 r;
    r.x = nid % gx;
    int t = nid / gx;
    r.y = t % gy;
    r.z = t / gy;
    return r;
}

#define AS1(p) ((__attribute__((address_space(1))) void*)(p))
#define AS3(p) ((__attribute__((address_space(3))) void*)(p))

// Self-detection: 1 if fp32 inputs, 0 if bf16. All lanes sample words 0..63 of x
// (identical ballot in every wave -> deterministic, no sync needed).
__device__ __forceinline__ int self_detect(const unsigned* __restrict__ xw, int tid) {
    unsigned w = xw[tid & 63];
    unsigned e = (w >> 7) & 0xFFu;
    unsigned long long b = __ballot(e >= 110 && e <= 140);
    return __popcll(b) < 32;
}

// ---------------- fused weight prep + LN1 (one kernel, R11) -------------------
// prep (blocks 0..793) and LN1 (blocks 794..) have no data dependency: LN1
// computes the dtype flag locally and reads RAW ln1_g/ln1_b -> the weight
// transposes overlap LN1's memory traffic and one launch gap disappears.
__device__ __forceinline__ void do_tr(const void* __restrict__ src, bf16* __restrict__ dst,
                                      int K, int N, int n0, int k0, int fl, int tid,
                                      bf16 (*tile)[65]) {
    int c = tid & 63, r4 = tid >> 6;
#pragma unroll
    for (int t = 0; t < 16; t++) {
        int r = t * 4 + r4;
        size_t si = (size_t)(k0 + r) * N + n0 + c;
        float v = fl ? ((const float*)src)[si] : b2f(((const bf16*)src)[si]);
        tile[r][c] = f2b(v);
    }
    __syncthreads();
#pragma unroll
    for (int t = 0; t < 16; t++) {
        int r = t * 4 + r4;
        dst[(size_t)(n0 + r) * K + k0 + c] = tile[c][r];
    }
}

__global__ void prep_ln_kernel(const void* x, const void* Wq, const void* Wk, const void* Wv,
                               const void* Wo, const void* W1, const void* W2,
                               const void* bq, const void* bk, const void* bv, const void* bo,
                               const void* b1, const void* b2,
                               const void* g1, const void* e1, const void* g2, const void* e2,
                               bf16* __restrict__ Wqkvt /* + Wot contiguous */,
                               bf16* __restrict__ W1t, bf16* __restrict__ W2t,
                               bf16* __restrict__ small, int* __restrict__ flag,
                               bf16* __restrict__ hb) {
    __shared__ bf16 tile[64][65];
    __shared__ float rs[4], rss[4], stat[2];
    int blk = blockIdx.x, tid = threadIdx.x;
    int fl = self_detect((const unsigned*)x, tid);
    if (blk == 0 && tid == 0) flag[0] = fl;   // publish for downstream kernels
    if (blk < 256) {                       // Wq|Wk|Wv|Wo 512x512
        int z = blk >> 6, tt = blk & 63;
        const void* src = (z == 0) ? Wq : (z == 1) ? Wk : (z == 2) ? Wv : Wo;
        do_tr(src, Wqkvt + (size_t)z * 512 * 512, 512, 512, (tt & 7) * 64, (tt >> 3) * 64,
              fl, tid, tile);
    } else if (blk < 512) {                // W1: [512][2048] -> [2048][512]
        int tt = blk - 256;
        do_tr(W1, W1t, 512, 2048, (tt & 31) * 64, (tt >> 5) * 64, fl, tid, tile);
    } else if (blk < 768) {                // W2: [2048][512] -> [512][2048]
        int tt = blk - 512;
        do_tr(W2, W2t, 2048, 512, (tt & 7) * 64, (tt >> 3) * 64, fl, tid, tile);
    } else if (blk < 794) {                // small vectors
        int i = (blk - 768) * 256 + tid;   // 0..6655
        const void* src; int off;
        if (i < 512)       { src = bq; off = 0; }
        else if (i < 1024) { src = bk; off = 512; }
        else if (i < 1536) { src = bv; off = 1024; }
        else if (i < 2048) { src = bo; off = 1536; }
        else if (i < 4096) { src = b1; off = 2048; }
        else if (i < 4608) { src = b2; off = 4096; }
        else if (i < 5120) { src = g1; off = 4608; }
        else if (i < 5632) { src = e1; off = 5120; }
        else if (i < 6144) { src = g2; off = 5632; }
        else               { src = e2; off = 6144; }
        int j = i - off;
        small[i] = fl ? f2b(((const float*)src)[j]) : ((const bf16*)src)[j];
    } else {                               // LN1 for token (blk-794), raw g/b
        int t = blk - 794;
        float v0, v1, gg0, gg1, bb0, bb1;
        if (fl) {
            const float* xr = (const float*)x + (size_t)t * D_MODEL;
            v0 = xr[tid]; v1 = xr[tid + 256];
            gg0 = ((const float*)g1)[tid]; gg1 = ((const float*)g1)[tid + 256];
            bb0 = ((const float*)e1)[tid]; bb1 = ((const float*)e1)[tid + 256];
        } else {
            const bf16* xr = (const bf16*)x + (size_t)t * D_MODEL;
            v0 = b2f(xr[tid]); v1 = b2f(xr[tid + 256]);
            gg0 = b2f(((const bf16*)g1)[tid]); gg1 = b2f(((const bf16*)g1)[tid + 256]);
            bb0 = b2f(((const bf16*)e1)[tid]); bb1 = b2f(((const bf16*)e1)[tid + 256]);
        }
        float s = v0 + v1, ss = v0 * v0 + v1 * v1;
        for (int o = 32; o > 0; o >>= 1) {
            s += __shfl_down(s, o);
            ss += __shfl_down(ss, o);
        }
        int w = tid >> 6, l = tid & 63;
        if (l == 0) { rs[w] = s; rss[w] = ss; }
        __syncthreads();
        if (tid == 0) {
            float S = rs[0] + rs[1] + rs[2] + rs[3];
            float SS = rss[0] + rss[1] + rss[2] + rss[3];
            float mu = S / (float)D_MODEL;
            float var = SS / (float)D_MODEL - mu * mu;
            stat[0] = mu;
            stat[1] = rsqrtf(var + 1e-5f);
        }
        __syncthreads();
        float mu = stat[0], rstd = stat[1];
        bf16* orow = hb + (size_t)t * D_MODEL;
        orow[tid]       = f2b((v0 - mu) * rstd * gg0 + bb0);
        orow[tid + 256] = f2b((v1 - mu) * rstd * gg1 + bb1);
    }
}

// ---------------- LayerNorm (LN2 only): one block per token -------------------
template <int MODE>
__global__ void ln_kernel(const void* __restrict__ xv, const bf16* __restrict__ g,
                          const bf16* __restrict__ b, bf16* __restrict__ out,
                          const int* __restrict__ flag) {
    int t = blockIdx.x;
    int tid = threadIdx.x;
    int fl = (MODE == 2) ? *flag : 0;
    float v0, v1;
    if (fl) {
        const float* xr = (const float*)xv + (size_t)t * D_MODEL;
        v0 = xr[tid]; v1 = xr[tid + 256];
    } else {
        const bf16* xr = (const bf16*)xv + (size_t)t * D_MODEL;
        v0 = b2f(xr[tid]); v1 = b2f(xr[tid + 256]);
    }
    float s = v0 + v1, ss = v0 * v0 + v1 * v1;
    for (int o = 32; o > 0; o >>= 1) {
        s += __shfl_down(s, o);
        ss += __shfl_down(ss, o);
    }
    __shared__ float rs[4], rss[4], stat[2];
    int w = tid >> 6, l = tid & 63;
    if (l == 0) { rs[w] = s; rss[w] = ss; }
    __syncthreads();
    if (tid == 0) {
        float S = rs[0] + rs[1] + rs[2] + rs[3];
        float SS = rss[0] + rss[1] + rss[2] + rss[3];
        float mu = S / (float)D_MODEL;
        float var = SS / (float)D_MODEL - mu * mu;
        stat[0] = mu;
        stat[1] = rsqrtf(var + 1e-5f);
    }
    __syncthreads();
    float mu = stat[0], rstd = stat[1];
    bf16* orow = out + (size_t)t * D_MODEL;
    orow[tid]       = f2b((v0 - mu) * rstd * b2f(g[tid])       + b2f(b[tid]));
    orow[tid + 256] = f2b((v1 - mu) * rstd * b2f(g[tid + 256]) + b2f(b[tid + 256]));
}

__device__ __forceinline__ float gelu_tanh(float v) {
    float u = 0.7978845608f * (v + 0.044715f * v * v * v);
    float e2 = __expf(-2.f * u);
    return v / (1.f + e2);
}

// ---------------- MFMA GEMM 128x64, BK=32 double-buffered 2-phase -------------
// R8's proven K-loop (plain __syncthreads; counted-vmcnt/raw-barrier variants
// all regressed). QKV 1536 blocks (6/CU), FFN1 2048 (6/CU), O/FFN2 512.
template <int ACT, int RES, int OUTMODE, int VT>
__global__ __launch_bounds__(256) void mfma_gemm64(
    const bf16* __restrict__ A, const bf16* __restrict__ Wt,
    const bf16* __restrict__ bias, const void* __restrict__ res,
    void* __restrict__ Cout, bf16* __restrict__ Vt_out,
    const int* __restrict__ flag, int M, int N, int K) {
    __shared__ bf16 As[2][128 * 32];
    __shared__ bf16 Bs[2][64 * 32];
    int tid = threadIdx.x, wave = tid >> 6, lane = tid & 63;
    int m = lane & 15, g = lane >> 4;
    int3 sw = swz_xyz();
    int row0 = sw.y * 128, col0 = sw.x * 64;
    int R0 = wave * 32;
    int fl = (OUTMODE == 2 || RES == 3) ? *flag : 0;
    float4v acc[2][4] = {};

    int srow = lane >> 2;            // 0..15
    int scol = (lane & 3) * 8;       // bf16 col 0/8/16/24
    const bf16* Ab = A  + (size_t)(row0 + wave * 32 + srow) * K + scol;
    const bf16* Bb = Wt + (size_t)(col0 + wave * 16 + srow) * K + scol;   // 16 rows/wave

#define GSTAGE64(buf, kk0)                                                         \
    {                                                                              \
        _Pragma("unroll")                                                          \
        for (int t = 0; t < 2; t++)                                                \
            __builtin_amdgcn_global_load_lds(AS1(Ab + (size_t)(t * 16) * K + (kk0)),\
                AS3(&As[buf][(wave * 32 + t * 16) * 32]), 16, 0, 0);               \
        __builtin_amdgcn_global_load_lds(AS1(Bb + (kk0)),                          \
            AS3(&Bs[buf][(wave * 16) * 32]), 16, 0, 0);                            \
    }

    int nk = K >> 5;
    GSTAGE64(0, 0);
    __syncthreads();
    for (int it = 0; it < nk; it++) {
        int cur = it & 1;
        if (it + 1 < nk) GSTAGE64(cur ^ 1, (it + 1) * 32);
        short8v fa[2], fb[4];
#pragma unroll
        for (int i = 0; i < 2; i++)
            fa[i] = *(const short8v*)&As[cur][(R0 + i * 16 + m) * 32 + g * 8];
#pragma unroll
        for (int j = 0; j < 4; j++)
            fb[j] = *(const short8v*)&Bs[cur][(j * 16 + m) * 32 + g * 8];
        __builtin_amdgcn_s_setprio(1);
#pragma unroll
        for (int i = 0; i < 2; i++)
#pragma unroll
            for (int j = 0; j < 4; j++)
                acc[i][j] = __builtin_amdgcn_mfma_f32_16x16x32_bf16(fa[i], fb[j], acc[i][j], 0, 0, 0);
        __builtin_amdgcn_s_setprio(0);
        __syncthreads();
    }
#undef GSTAGE64

    if (VT && col0 >= 1024) {
        // V-part of QKV: write transposed into Vt_g [bh][64][SEQ_LEN].
#pragma unroll
        for (int i = 0; i < 2; i++) {
            int row = row0 + R0 + i * 16 + g * 4;
            int b = row >> 12, s = row & (SEQ_LEN - 1);
#pragma unroll
            for (int j = 0; j < 4; j++) {
                int col = col0 + j * 16 + m;
                int hh = (col - 1024) >> 6, d = col & 63;
                float bi = b2f(bias[col]);
                pack_u oo;
                oo.u[0] = pack_bf16(acc[i][j][0] + bi, acc[i][j][1] + bi);
                oo.u[1] = pack_bf16(acc[i][j][2] + bi, acc[i][j][3] + bi);
                *(short4v*)&Vt_out[((size_t)((b << 3) + hh) * 64 + d) * SEQ_LEN + s] = oo.v4;
            }
        }
        return;
    }

#pragma unroll
    for (int i = 0; i < 2; i++) {
#pragma unroll
        for (int r = 0; r < 4; r++) {
            int row = row0 + R0 + i * 16 + g * 4 + r;
#pragma unroll
            for (int j = 0; j < 4; j++) {
                int col = col0 + j * 16 + m;
                float v = acc[i][j][r] + b2f(bias[col]);
                if (ACT == 1) v = gelu_tanh(v);
                size_t idx = (size_t)row * N + col;
                if (RES == 2) v += b2f(((const bf16*)res)[idx]);
                if (RES == 3) v += fl ? ((const float*)res)[idx]
                                      : b2f(((const bf16*)res)[idx]);
                if (OUTMODE == 0) ((bf16*)Cout)[idx] = f2b(v);
                else {
                    if (fl) ((float*)Cout)[idx] = v;
                    else ((bf16*)Cout)[idx] = f2b(v);
                }
            }
        }
    }
}

// ---------------- Flash attention, S^T formulation, 32q/wave, split-K=KS ------
// Unchanged (plateaued ~110us: VALU near algorithmic floor, register-capped).
#define F3(a, b, c) fmaxf(fmaxf((a), (b)), (c))
template <int KS>
__global__ __launch_bounds__(256, 4) void flash_attn(const bf16* __restrict__ Q,
                                                     const bf16* __restrict__ K,
                                                     const bf16* __restrict__ Vt_g,
                                                     bf16* __restrict__ Op,
                                                     float2* __restrict__ mlout) {
    __shared__ bf16 Ks[64][72];      // overlaid by per-wave Pt[16][72] after barrier A
    __shared__ bf16 Vt[64][72];

    int tid = threadIdx.x;
    int wave = tid >> 6, lane = tid & 63;
    int m = lane & 15, g = lane >> 4;
    bf16* PtW = &Ks[0][0] + wave * (16 * 72);   // wave-exclusive 2304B overlay

    int3 sw = swz_xyz();
    int bh = sw.y;
    size_t base = (size_t)(bh >> 3) * SEQ_LEN * QKV_STRIDE + (size_t)(bh & 7) * HEAD_DIM;
    int q0w = sw.x * 128 + wave * 32;

    const float qscale = 0.125f * 1.44269504f;   // fold log2(e) -> exp2 softmax
    short8v aQ[2][2];
#pragma unroll
    for (int mt = 0; mt < 2; mt++) {
        const bf16* qp = Q + base + (size_t)(q0w + mt * 16 + m) * QKV_STRIDE + g * 8;
#pragma unroll
        for (int c = 0; c < 2; c++) {
            frag_u u;
#pragma unroll
            for (int j = 0; j < 8; j++) u.s[j] = f2bs(b2f(qp[c * 32 + j]) * qscale);
            aQ[mt][c] = u.v8;
        }
    }

    float mrow[2] = {-1e30f, -1e30f};
    float lrow[2] = {0.f, 0.f};
    float4v oacc[2][4] = {};

    int sk = tid >> 2, sd = (tid & 3) * 16;
    int vrow = tid >> 2, vcol = (tid & 3) * 16;

    const unsigned short* Ku = (const unsigned short*)(K + base);
    const unsigned short* Vg = (const unsigned short*)Vt_g +
                               (size_t)bh * 64 * SEQ_LEN + (size_t)vrow * SEQ_LEN;

    int t0 = sw.z * (64 / KS);
    int t1 = t0 + 64 / KS;

    // staging registers (single-buffered: load t+1 -> compute t -> store t+1)
    short8v rk0, rk1, rv0, rv1;
    {   // prologue: tile t0 global -> regs -> LDS
        int kt0 = t0 * 64;
        const unsigned short* kp = Ku + (size_t)(kt0 + sk) * QKV_STRIDE + sd;
        rk0 = *(const short8v*)(kp);
        rk1 = *(const short8v*)(kp + 8);
        rv0 = *(const short8v*)(Vg + kt0 + vcol);
        rv1 = *(const short8v*)(Vg + kt0 + vcol + 8);
        *(short8v*)&Ks[sk][sd]     = rk0;
        *(short8v*)&Ks[sk][sd + 8] = rk1;
        *(short8v*)&Vt[vrow][vcol]     = rv0;
        *(short8v*)&Vt[vrow][vcol + 8] = rv1;
    }
    __syncthreads();

    for (int t = t0; t < t1; t++) {
        // T14 issue-early: next tile's global loads go in flight NOW.
        if (t + 1 < t1) {
            int ktn = (t + 1) * 64;
            const unsigned short* kp = Ku + (size_t)(ktn + sk) * QKV_STRIDE + sd;
            rk0 = *(const short8v*)(kp);
            rk1 = *(const short8v*)(kp + 8);
            rv0 = *(const short8v*)(Vg + ktn + vcol);
            rv1 = *(const short8v*)(Vg + ktn + vcol + 8);
        }

        // QK^T: per kt load K frags once, use for both m-tiles
        float4v st[2][4];
        __builtin_amdgcn_s_setprio(1);
#pragma unroll
        for (int kt = 0; kt < 4; kt++) {
            short8v bK0 = *(const short8v*)&Ks[kt * 16 + m][g * 8];
            short8v bK1 = *(const short8v*)&Ks[kt * 16 + m][32 + g * 8];
#pragma unroll
            for (int mt = 0; mt < 2; mt++) {
                float4v a = {0.f, 0.f, 0.f, 0.f};
                a = __builtin_amdgcn_mfma_f32_16x16x32_bf16(bK0, aQ[mt][0], a, 0, 0, 0);
                a = __builtin_amdgcn_mfma_f32_16x16x32_bf16(bK1, aQ[mt][1], a, 0, 0, 0);
                st[mt][kt] = a;
            }
        }
        __builtin_amdgcn_s_setprio(0);

        __syncthreads();   // barrier A: ALL waves' Ks reads done -> Pt may overlay

        // online softmax per m-tile (exp2 domain, defer-max); Pt in Ks overlay
        short8v bP[2][2];
#pragma unroll
        for (int mt = 0; mt < 2; mt++) {
            float u0 = F3(st[mt][0][0], st[mt][0][1], st[mt][0][2]);
            float u1 = F3(st[mt][0][3], st[mt][1][0], st[mt][1][1]);
            float u2 = F3(st[mt][1][2], st[mt][1][3], st[mt][2][0]);
            float u3 = F3(st[mt][2][1], st[mt][2][2], st[mt][2][3]);
            float u4 = F3(st[mt][3][0], st[mt][3][1], st[mt][3][2]);
            float tm = fmaxf(F3(u0, u1, u2), F3(u3, u4, st[mt][3][3]));
            tm = fmaxf(tm, __shfl_xor(tm, 16));
            tm = fmaxf(tm, __shfl_xor(tm, 32));
            // T13 defer-max: only rescale when the max grew by > 8 (exp2 dom).
            if (!__all(tm - mrow[mt] <= 8.f)) {
                float mnew = fmaxf(mrow[mt], tm);
                float alpha = exp2fast(mrow[mt] - mnew);
                mrow[mt] = mnew;
                lrow[mt] *= alpha;
#pragma unroll
                for (int dt = 0; dt < 4; dt++)
#pragma unroll
                    for (int r = 0; r < 4; r++) oacc[mt][dt][r] *= alpha;
            }
            float mcur = mrow[mt];
            float2v ps = {0.f, 0.f};
#pragma unroll
            for (int kt = 0; kt < 4; kt++) {
                float p0 = exp2fast(st[mt][kt][0] - mcur);
                float p1 = exp2fast(st[mt][kt][1] - mcur);
                float p2 = exp2fast(st[mt][kt][2] - mcur);
                float p3 = exp2fast(st[mt][kt][3] - mcur);
                float2v a = {p0, p1}, b = {p2, p3};
                ps += a + b;                       // v_pk_add_f32
                pack_u pp;
                pp.u[0] = cvt_pk_bf16(p0, p1);
                pp.u[1] = cvt_pk_bf16(p2, p3);
                *(short4v*)&PtW[m * 72 + kt * 16 + g * 4] = pp.v4;
            }
            lrow[mt] += ps[0] + ps[1];
            // read back this mt's P^T frags (same wave; lgkmcnt orders it),
            // then the 16-row region is reused by mt=1.
#pragma unroll
            for (int c = 0; c < 2; c++)
                bP[mt][c] = *(const short8v*)&PtW[m * 72 + c * 32 + g * 8];
        }

        // PV: Vt A-frags loaded once, used for both m-tiles
        __builtin_amdgcn_s_setprio(1);
#pragma unroll
        for (int dt = 0; dt < 4; dt++) {
#pragma unroll
            for (int c = 0; c < 2; c++) {
                short8v av = *(const short8v*)&Vt[dt * 16 + m][c * 32 + g * 8];
#pragma unroll
                for (int mt = 0; mt < 2; mt++)
                    oacc[mt][dt] = __builtin_amdgcn_mfma_f32_16x16x32_bf16(av, bP[mt][c], oacc[mt][dt], 0, 0, 0);
            }
        }
        __builtin_amdgcn_s_setprio(0);

        __syncthreads();   // barrier B: PV Vt reads + all Pt reads done
        // T14 write-late: regs (already landed during compute) -> LDS
        if (t + 1 < t1) {
            *(short8v*)&Ks[sk][sd]     = rk0;   // overwrites the Pt overlay
            *(short8v*)&Ks[sk][sd + 8] = rk1;
            *(short8v*)&Vt[vrow][vcol]     = rv0;
            *(short8v*)&Vt[vrow][vcol + 8] = rv1;
        }
        __syncthreads();   // barrier C: staged tile t+1 visible
    }

    size_t zoff = (size_t)sw.z * NUM_HEADS * BATCH + bh;
    size_t pbase = zoff * (SEQ_LEN * (size_t)HEAD_DIM);
#pragma unroll
    for (int mt = 0; mt < 2; mt++) {
        float l = lrow[mt];
        l += __shfl_xor(l, 16);
        l += __shfl_xor(l, 32);
        int q = q0w + mt * 16 + m;
        bf16* orow = Op + pbase + (size_t)q * HEAD_DIM;
#pragma unroll
        for (int dt = 0; dt < 4; dt++) {
            pack_u oo;
            oo.u[0] = cvt_pk_bf16(oacc[mt][dt][0], oacc[mt][dt][1]);
            oo.u[1] = cvt_pk_bf16(oacc[mt][dt][2], oacc[mt][dt][3]);
            *(short4v*)&orow[dt * 16 + g * 4] = oo.v4;
        }
        if (g == 0) mlout[zoff * SEQ_LEN + q] = make_float2(mrow[mt], l);
    }
}

// Merge KS partials -> attention output ab [TOKENS][D_MODEL] (exp2 domain).
// R13: vectorized 8 bf16/thread (was 1/thread scalar — Common-mistake #2):
// 16B loads from each partial, 16B store, 8x fewer blocks.
template <int KS>
__global__ void attn_merge(const bf16* __restrict__ Op, const float2* __restrict__ ml,
                           bf16* __restrict__ O) {
    int i = (blockIdx.x * 256 + threadIdx.x) * 8;   // over 16*4096*64, step 8
    int d = i & 63;
    int q = (i >> 6) & (SEQ_LEN - 1);
    int bh = i >> 18;
    const int HQ = NUM_HEADS * BATCH * SEQ_LEN;
    float2 a[KS];
    float M = -1e30f;
#pragma unroll
    for (int p = 0; p < KS; p++) {
        a[p] = ml[(size_t)p * HQ + bh * SEQ_LEN + q];
        M = fmaxf(M, a[p].x);
    }
    float w[KS];
    float denom = 0.f;
#pragma unroll
    for (int p = 0; p < KS; p++) {
        w[p] = exp2fast(a[p].x - M);
        denom += a[p].y * w[p];
    }
    float inv = 1.f / denom;
    const size_t NP = (size_t)HQ * HEAD_DIM;
    frag_u u[KS];
#pragma unroll
    for (int p = 0; p < KS; p++) u[p].v8 = *(const short8v*)&Op[(size_t)p * NP + i];
    pack8_u out;
#pragma unroll
    for (int j = 0; j < 4; j++) {
        float lo = 0.f, hi = 0.f;
#pragma unroll
        for (int p = 0; p < KS; p++) {
            lo += bs2f(u[p].s[2 * j])     * w[p];
            hi += bs2f(u[p].s[2 * j + 1]) * w[p];
        }
        out.u[j] = cvt_pk_bf16(lo * inv, hi * inv);
    }
    *(short8v*)&O[((size_t)((bh >> 3) * SEQ_LEN + q)) * D_MODEL + (bh & 7) * HEAD_DIM + d] = out.v8;
}

// ------------------------------------------------------------------------------
extern "C" void kernel_launch(void* const* d_in, const int* in_sizes, int n_in,
                              void* d_out, int out_size, void* d_ws, size_t ws_size,
                              hipStream_t stream) {
    const void* x     = d_in[0];
    const void* Wq    = d_in[1];
    const void* bq    = d_in[2];
    const void* Wk    = d_in[3];
    const void* bk    = d_in[4];
    const void* Wv    = d_in[5];
    const void* bv    = d_in[6];
    const void* Wo    = d_in[7];
    const void* bo    = d_in[8];
    const void* ln1_g = d_in[9];
    const void* ln1_b = d_in[10];
    const void* ln2_g = d_in[11];
    const void* ln2_b = d_in[12];
    const void* W1    = d_in[13];
    const void* b1    = d_in[14];
    const void* W2    = d_in[15];
    const void* b2    = d_in[16];

    // ---- workspace layout ----
    char* p = (char*)d_ws;
    int* flag = (int*)p;                      p += 256;
    size_t tok_d = (size_t)TOKENS * D_MODEL;
    // region2: KSPLIT bf16 O-partials (16.8 MB) overlay x1b+hb (16.8 MB)
    char* region2 = p;                        p += 2 * tok_d * 2;
    bf16* x1b   = (bf16*)region2;                              // [TOKENS][512]
    bf16* hb    = (bf16*)(region2 + tok_d * 2);                // [TOKENS][512]
    bf16* Opart = (bf16*)region2;
    bf16*  bigA = (bf16*)p;                   p += (size_t)TOKENS * D_FF * 2;  // 33.6 MB
    bf16*  qkvb = bigA;                                   // [TOKENS][1536]
    bf16*  ab   = bigA + (size_t)TOKENS * QKV_STRIDE;     // [TOKENS][512]
    bf16*  ffb  = bigA;                                   // [TOKENS][2048]
    bf16*  Wqkvt = (bf16*)p;                  p += (size_t)QKV_STRIDE * D_MODEL * 2;
    bf16*  Wot   = (bf16*)p;                  p += (size_t)D_MODEL * D_MODEL * 2;  // contiguous
    bf16*  W1t   = (bf16*)p;                  p += (size_t)D_FF * D_MODEL * 2;
    bf16*  W2t   = (bf16*)p;                  p += (size_t)D_MODEL * D_FF * 2;
    bf16*  Vtg   = (bf16*)p;                  p += (size_t)NUM_HEADS * BATCH * HEAD_DIM * SEQ_LEN * 2;
    float2* mlb  = (float2*)p;                p += (size_t)KSPLIT * NUM_HEADS * BATCH * SEQ_LEN * sizeof(float2);
    bf16*  small = (bf16*)p;                  p += 6656 * 2;
    bf16* bias_qkv = small + 0;
    bf16* bias_o   = small + 1536;
    bf16* b1b      = small + 2048;
    bf16* b2b      = small + 4096;
    bf16* g1b      = small + 4608;
    bf16* be1b     = small + 5120;
    bf16* g2b      = small + 5632;
    bf16* be2b     = small + 6144;
    (void)g1b; (void)be1b;

    // fused prep + LN1 (LN1 reads raw x and raw ln1_g/ln1_b; flag via self_detect)
    prep_ln_kernel<<<794 + TOKENS, 256, 0, stream>>>(
        x, Wq, Wk, Wv, Wo, W1, W2, bq, bk, bv, bo, b1, b2,
        ln1_g, ln1_b, ln2_g, ln2_b, Wqkvt, W1t, W2t, small, flag, hb);

    // fused QKV projection (64-col tiles, 1536 blocks = 6/CU);
    // V part written transposed straight into Vtg
    mfma_gemm64<0, 0, 0, 1><<<dim3(QKV_STRIDE / 64, TOKENS / 128), 256, 0, stream>>>(
        hb, Wqkvt, bias_qkv, nullptr, qkvb, Vtg, flag, TOKENS, QKV_STRIDE, D_MODEL);

    flash_attn<KSPLIT><<<dim3(SEQ_LEN / 128, 16, KSPLIT), 256, 0, stream>>>(
        qkvb, qkvb + 512, Vtg, Opart, mlb);
    attn_merge<KSPLIT><<<(NUM_HEADS * BATCH * SEQ_LEN * HEAD_DIM) / (256 * 8), 256, 0, stream>>>(
        Opart, mlb, ab);

    // O projection + residual(raw x) -> x1 (bf16); 512 blocks
    mfma_gemm64<0, 3, 0, 0><<<dim3(D_MODEL / 64, TOKENS / 128), 256, 0, stream>>>(
        ab, Wot, bias_o, x, x1b, nullptr, flag, TOKENS, D_MODEL, D_MODEL);

    ln_kernel<0><<<TOKENS, 256, 0, stream>>>(x1b, g2b, be2b, hb, flag);

    // FFN1 + GELU (64-col tiles, 2048 blocks = 6/CU)
    mfma_gemm64<1, 0, 0, 0><<<dim3(D_FF / 64, TOKENS / 128), 256, 0, stream>>>(
        hb, W1t, b1b, nullptr, ffb, nullptr, flag, TOKENS, D_FF, D_MODEL);

    // FFN2 + residual(x1 bf16) -> out (dtype per flag); 512 blocks
    mfma_gemm64<0, 2, 2, 0><<<dim3(D_MODEL / 64, TOKENS / 128), 256, 0, stream>>>(
        ffb, W2t, b2b, x1b, d_out, nullptr, flag, TOKENS, D_MODEL, D_FF);
}

// Round 14
// 335.864 us; speedup vs baseline: 1.0168x; 1.0146x over previous
//
#include <hip/hip_runtime.h>
#include <hip/hip_bf16.h>
#include <math.h>

typedef __hip_bfloat16 bf16;

#define D_MODEL 512
#define NUM_HEADS 8
#define HEAD_DIM 64
#define SEQ_LEN 4096
#define BATCH 2
#define D_FF 2048
#define TOKENS (BATCH * SEQ_LEN)
#define QKV_STRIDE 1536
#define KSPLIT 2

typedef short short4v __attribute__((ext_vector_type(4)));
typedef short short8v __attribute__((ext_vector_type(8)));
typedef float float4v __attribute__((ext_vector_type(4)));
typedef float float2v __attribute__((ext_vector_type(2)));

union frag_u { short8v v8; short4v v4[2]; short s[8]; };
union pack_u { unsigned u[2]; short4v v4; };

__device__ __forceinline__ float b2f(bf16 v) { return __bfloat162float(v); }
__device__ __forceinline__ bf16 f2b(float v) { return __float2bfloat16(v); }
__device__ __forceinline__ short f2bs(float v) { bf16 t = __float2bfloat16(v); return *(short*)&t; }
__device__ __forceinline__ float exp2fast(float x) { return __builtin_amdgcn_exp2f(x); }

// pack two f32 -> (bf16(hi)<<16)|bf16(lo), round-to-nearest via +0x8000 + v_perm
__device__ __forceinline__ unsigned pack_bf16(float lo, float hi) {
    unsigned a = __float_as_uint(hi) + 0x8000u;
    unsigned b = __float_as_uint(lo) + 0x8000u;
    return __builtin_amdgcn_perm(a, b, 0x07060302u);
}

// T12 primitive: single-instruction pack (RNE). No builtin on gfx950 -> asm.
__device__ __forceinline__ unsigned cvt_pk_bf16(float lo, float hi) {
    unsigned r;
    asm("v_cvt_pk_bf16_f32 %0, %1, %2" : "=v"(r) : "v"(lo), "v"(hi));
    return r;
}

// T1: bijective XCD-aware block swizzle (requires nwg % 8 == 0; all our grids are).
__device__ __forceinline__ int3 swz_xyz() {
    int gx = gridDim.x, gy = gridDim.y;
    int id = blockIdx.x + gx * (blockIdx.y + gy * blockIdx.z);
    int nwg = gx * gy * (int)gridDim.z;
    int nid = (id & 7) * (nwg >> 3) + (id >> 3);
    int3 r;
    r.x = nid % gx;
    int t = nid / gx;
    r.y = t % gy;
    r.z = t / gy;
    return r;
}

#define AS1(p) ((__attribute__((address_space(1))) void*)(p))
#define AS3(p) ((__attribute__((address_space(3))) void*)(p))

// Self-detection: 1 if fp32 inputs, 0 if bf16. All lanes sample words 0..63 of x
// (identical ballot in every wave -> deterministic, no sync needed).
__device__ __forceinline__ int self_detect(const unsigned* __restrict__ xw, int tid) {
    unsigned w = xw[tid & 63];
    unsigned e = (w >> 7) & 0xFFu;
    unsigned long long b = __ballot(e >= 110 && e <= 140);
    return __popcll(b) < 32;
}

// ---------------- fused weight prep + LN1 (one kernel, R11) -------------------
// prep (blocks 0..793) and LN1 (blocks 794..) have no data dependency: LN1
// computes the dtype flag locally and reads RAW ln1_g/ln1_b -> the weight
// transposes overlap LN1's memory traffic and one launch gap disappears.
__device__ __forceinline__ void do_tr(const void* __restrict__ src, bf16* __restrict__ dst,
                                      int K, int N, int n0, int k0, int fl, int tid,
                                      bf16 (*tile)[65]) {
    int c = tid & 63, r4 = tid >> 6;
#pragma unroll
    for (int t = 0; t < 16; t++) {
        int r = t * 4 + r4;
        size_t si = (size_t)(k0 + r) * N + n0 + c;
        float v = fl ? ((const float*)src)[si] : b2f(((const bf16*)src)[si]);
        tile[r][c] = f2b(v);
    }
    __syncthreads();
#pragma unroll
    for (int t = 0; t < 16; t++) {
        int r = t * 4 + r4;
        dst[(size_t)(n0 + r) * K + k0 + c] = tile[c][r];
    }
}

__global__ void prep_ln_kernel(const void* x, const void* Wq, const void* Wk, const void* Wv,
                               const void* Wo, const void* W1, const void* W2,
                               const void* bq, const void* bk, const void* bv, const void* bo,
                               const void* b1, const void* b2,
                               const void* g1, const void* e1, const void* g2, const void* e2,
                               bf16* __restrict__ Wqkvt /* + Wot contiguous */,
                               bf16* __restrict__ W1t, bf16* __restrict__ W2t,
                               bf16* __restrict__ small, int* __restrict__ flag,
                               bf16* __restrict__ hb) {
    __shared__ bf16 tile[64][65];
    __shared__ float rs[4], rss[4], stat[2];
    int blk = blockIdx.x, tid = threadIdx.x;
    int fl = self_detect((const unsigned*)x, tid);
    if (blk == 0 && tid == 0) flag[0] = fl;   // publish for downstream kernels
    if (blk < 256) {                       // Wq|Wk|Wv|Wo 512x512
        int z = blk >> 6, tt = blk & 63;
        const void* src = (z == 0) ? Wq : (z == 1) ? Wk : (z == 2) ? Wv : Wo;
        do_tr(src, Wqkvt + (size_t)z * 512 * 512, 512, 512, (tt & 7) * 64, (tt >> 3) * 64,
              fl, tid, tile);
    } else if (blk < 512) {                // W1: [512][2048] -> [2048][512]
        int tt = blk - 256;
        do_tr(W1, W1t, 512, 2048, (tt & 31) * 64, (tt >> 5) * 64, fl, tid, tile);
    } else if (blk < 768) {                // W2: [2048][512] -> [512][2048]
        int tt = blk - 512;
        do_tr(W2, W2t, 2048, 512, (tt & 7) * 64, (tt >> 3) * 64, fl, tid, tile);
    } else if (blk < 794) {                // small vectors
        int i = (blk - 768) * 256 + tid;   // 0..6655
        const void* src; int off;
        if (i < 512)       { src = bq; off = 0; }
        else if (i < 1024) { src = bk; off = 512; }
        else if (i < 1536) { src = bv; off = 1024; }
        else if (i < 2048) { src = bo; off = 1536; }
        else if (i < 4096) { src = b1; off = 2048; }
        else if (i < 4608) { src = b2; off = 4096; }
        else if (i < 5120) { src = g1; off = 4608; }
        else if (i < 5632) { src = e1; off = 5120; }
        else if (i < 6144) { src = g2; off = 5632; }
        else               { src = e2; off = 6144; }
        int j = i - off;
        small[i] = fl ? f2b(((const float*)src)[j]) : ((const bf16*)src)[j];
    } else {                               // LN1 for token (blk-794), raw g/b
        int t = blk - 794;
        float v0, v1, gg0, gg1, bb0, bb1;
        if (fl) {
            const float* xr = (const float*)x + (size_t)t * D_MODEL;
            v0 = xr[tid]; v1 = xr[tid + 256];
            gg0 = ((const float*)g1)[tid]; gg1 = ((const float*)g1)[tid + 256];
            bb0 = ((const float*)e1)[tid]; bb1 = ((const float*)e1)[tid + 256];
        } else {
            const bf16* xr = (const bf16*)x + (size_t)t * D_MODEL;
            v0 = b2f(xr[tid]); v1 = b2f(xr[tid + 256]);
            gg0 = b2f(((const bf16*)g1)[tid]); gg1 = b2f(((const bf16*)g1)[tid + 256]);
            bb0 = b2f(((const bf16*)e1)[tid]); bb1 = b2f(((const bf16*)e1)[tid + 256]);
        }
        float s = v0 + v1, ss = v0 * v0 + v1 * v1;
        for (int o = 32; o > 0; o >>= 1) {
            s += __shfl_down(s, o);
            ss += __shfl_down(ss, o);
        }
        int w = tid >> 6, l = tid & 63;
        if (l == 0) { rs[w] = s; rss[w] = ss; }
        __syncthreads();
        if (tid == 0) {
            float S = rs[0] + rs[1] + rs[2] + rs[3];
            float SS = rss[0] + rss[1] + rss[2] + rss[3];
            float mu = S / (float)D_MODEL;
            float var = SS / (float)D_MODEL - mu * mu;
            stat[0] = mu;
            stat[1] = rsqrtf(var + 1e-5f);
        }
        __syncthreads();
        float mu = stat[0], rstd = stat[1];
        bf16* orow = hb + (size_t)t * D_MODEL;
        orow[tid]       = f2b((v0 - mu) * rstd * gg0 + bb0);
        orow[tid + 256] = f2b((v1 - mu) * rstd * gg1 + bb1);
    }
}

// ---------------- LayerNorm (LN2 only): one block per token -------------------
template <int MODE>
__global__ void ln_kernel(const void* __restrict__ xv, const bf16* __restrict__ g,
                          const bf16* __restrict__ b, bf16* __restrict__ out,
                          const int* __restrict__ flag) {
    int t = blockIdx.x;
    int tid = threadIdx.x;
    int fl = (MODE == 2) ? *flag : 0;
    float v0, v1;
    if (fl) {
        const float* xr = (const float*)xv + (size_t)t * D_MODEL;
        v0 = xr[tid]; v1 = xr[tid + 256];
    } else {
        const bf16* xr = (const bf16*)xv + (size_t)t * D_MODEL;
        v0 = b2f(xr[tid]); v1 = b2f(xr[tid + 256]);
    }
    float s = v0 + v1, ss = v0 * v0 + v1 * v1;
    for (int o = 32; o > 0; o >>= 1) {
        s += __shfl_down(s, o);
        ss += __shfl_down(ss, o);
    }
    __shared__ float rs[4], rss[4], stat[2];
    int w = tid >> 6, l = tid & 63;
    if (l == 0) { rs[w] = s; rss[w] = ss; }
    __syncthreads();
    if (tid == 0) {
        float S = rs[0] + rs[1] + rs[2] + rs[3];
        float SS = rss[0] + rss[1] + rss[2] + rss[3];
        float mu = S / (float)D_MODEL;
        float var = SS / (float)D_MODEL - mu * mu;
        stat[0] = mu;
        stat[1] = rsqrtf(var + 1e-5f);
    }
    __syncthreads();
    float mu = stat[0], rstd = stat[1];
    bf16* orow = out + (size_t)t * D_MODEL;
    orow[tid]       = f2b((v0 - mu) * rstd * b2f(g[tid])       + b2f(b[tid]));
    orow[tid + 256] = f2b((v1 - mu) * rstd * b2f(g[tid + 256]) + b2f(b[tid + 256]));
}

__device__ __forceinline__ float gelu_tanh(float v) {
    float u = 0.7978845608f * (v + 0.044715f * v * v * v);
    float e2 = __expf(-2.f * u);
    return v / (1.f + e2);
}

// ---------------- MFMA GEMM 128x64, BK=32 double-buffered 2-phase -------------
// R8's proven K-loop (plain __syncthreads; counted-vmcnt/raw-barrier variants
// all regressed). QKV 1536 blocks (6/CU), FFN1 2048 (6/CU), O/FFN2 512.
template <int ACT, int RES, int OUTMODE, int VT>
__global__ __launch_bounds__(256) void mfma_gemm64(
    const bf16* __restrict__ A, const bf16* __restrict__ Wt,
    const bf16* __restrict__ bias, const void* __restrict__ res,
    void* __restrict__ Cout, bf16* __restrict__ Vt_out,
    const int* __restrict__ flag, int M, int N, int K) {
    __shared__ bf16 As[2][128 * 32];
    __shared__ bf16 Bs[2][64 * 32];
    int tid = threadIdx.x, wave = tid >> 6, lane = tid & 63;
    int m = lane & 15, g = lane >> 4;
    int3 sw = swz_xyz();
    int row0 = sw.y * 128, col0 = sw.x * 64;
    int R0 = wave * 32;
    int fl = (OUTMODE == 2 || RES == 3) ? *flag : 0;
    float4v acc[2][4] = {};

    int srow = lane >> 2;            // 0..15
    int scol = (lane & 3) * 8;       // bf16 col 0/8/16/24
    const bf16* Ab = A  + (size_t)(row0 + wave * 32 + srow) * K + scol;
    const bf16* Bb = Wt + (size_t)(col0 + wave * 16 + srow) * K + scol;   // 16 rows/wave

#define GSTAGE64(buf, kk0)                                                         \
    {                                                                              \
        _Pragma("unroll")                                                          \
        for (int t = 0; t < 2; t++)                                                \
            __builtin_amdgcn_global_load_lds(AS1(Ab + (size_t)(t * 16) * K + (kk0)),\
                AS3(&As[buf][(wave * 32 + t * 16) * 32]), 16, 0, 0);               \
        __builtin_amdgcn_global_load_lds(AS1(Bb + (kk0)),                          \
            AS3(&Bs[buf][(wave * 16) * 32]), 16, 0, 0);                            \
    }

    int nk = K >> 5;
    GSTAGE64(0, 0);
    __syncthreads();
    for (int it = 0; it < nk; it++) {
        int cur = it & 1;
        if (it + 1 < nk) GSTAGE64(cur ^ 1, (it + 1) * 32);
        short8v fa[2], fb[4];
#pragma unroll
        for (int i = 0; i < 2; i++)
            fa[i] = *(const short8v*)&As[cur][(R0 + i * 16 + m) * 32 + g * 8];
#pragma unroll
        for (int j = 0; j < 4; j++)
            fb[j] = *(const short8v*)&Bs[cur][(j * 16 + m) * 32 + g * 8];
        __builtin_amdgcn_s_setprio(1);
#pragma unroll
        for (int i = 0; i < 2; i++)
#pragma unroll
            for (int j = 0; j < 4; j++)
                acc[i][j] = __builtin_amdgcn_mfma_f32_16x16x32_bf16(fa[i], fb[j], acc[i][j], 0, 0, 0);
        __builtin_amdgcn_s_setprio(0);
        __syncthreads();
    }
#undef GSTAGE64

    if (VT && col0 >= 1024) {
        // V-part of QKV: write transposed into Vt_g [bh][64][SEQ_LEN].
#pragma unroll
        for (int i = 0; i < 2; i++) {
            int row = row0 + R0 + i * 16 + g * 4;
            int b = row >> 12, s = row & (SEQ_LEN - 1);
#pragma unroll
            for (int j = 0; j < 4; j++) {
                int col = col0 + j * 16 + m;
                int hh = (col - 1024) >> 6, d = col & 63;
                float bi = b2f(bias[col]);
                pack_u oo;
                oo.u[0] = pack_bf16(acc[i][j][0] + bi, acc[i][j][1] + bi);
                oo.u[1] = pack_bf16(acc[i][j][2] + bi, acc[i][j][3] + bi);
                *(short4v*)&Vt_out[((size_t)((b << 3) + hh) * 64 + d) * SEQ_LEN + s] = oo.v4;
            }
        }
        return;
    }

#pragma unroll
    for (int i = 0; i < 2; i++) {
#pragma unroll
        for (int r = 0; r < 4; r++) {
            int row = row0 + R0 + i * 16 + g * 4 + r;
#pragma unroll
            for (int j = 0; j < 4; j++) {
                int col = col0 + j * 16 + m;
                float v = acc[i][j][r] + b2f(bias[col]);
                if (ACT == 1) v = gelu_tanh(v);
                size_t idx = (size_t)row * N + col;
                if (RES == 2) v += b2f(((const bf16*)res)[idx]);
                if (RES == 3) v += fl ? ((const float*)res)[idx]
                                      : b2f(((const bf16*)res)[idx]);
                if (OUTMODE == 0) ((bf16*)Cout)[idx] = f2b(v);
                else {
                    if (fl) ((float*)Cout)[idx] = v;
                    else ((bf16*)Cout)[idx] = f2b(v);
                }
            }
        }
    }
}

// ---------------- Flash attention, S^T formulation, 32q/wave, split-K=KS ------
// Plateaued ~107-110us: VALU near algorithmic floor, register-capped residency.
#define F3(a, b, c) fmaxf(fmaxf((a), (b)), (c))
template <int KS>
__global__ __launch_bounds__(256, 4) void flash_attn(const bf16* __restrict__ Q,
                                                     const bf16* __restrict__ K,
                                                     const bf16* __restrict__ Vt_g,
                                                     bf16* __restrict__ Op,
                                                     float2* __restrict__ mlout) {
    __shared__ bf16 Ks[64][72];      // overlaid by per-wave Pt[16][72] after barrier A
    __shared__ bf16 Vt[64][72];

    int tid = threadIdx.x;
    int wave = tid >> 6, lane = tid & 63;
    int m = lane & 15, g = lane >> 4;
    bf16* PtW = &Ks[0][0] + wave * (16 * 72);   // wave-exclusive 2304B overlay

    int3 sw = swz_xyz();
    int bh = sw.y;
    size_t base = (size_t)(bh >> 3) * SEQ_LEN * QKV_STRIDE + (size_t)(bh & 7) * HEAD_DIM;
    int q0w = sw.x * 128 + wave * 32;

    const float qscale = 0.125f * 1.44269504f;   // fold log2(e) -> exp2 softmax
    short8v aQ[2][2];
#pragma unroll
    for (int mt = 0; mt < 2; mt++) {
        const bf16* qp = Q + base + (size_t)(q0w + mt * 16 + m) * QKV_STRIDE + g * 8;
#pragma unroll
        for (int c = 0; c < 2; c++) {
            frag_u u;
#pragma unroll
            for (int j = 0; j < 8; j++) u.s[j] = f2bs(b2f(qp[c * 32 + j]) * qscale);
            aQ[mt][c] = u.v8;
        }
    }

    float mrow[2] = {-1e30f, -1e30f};
    float lrow[2] = {0.f, 0.f};
    float4v oacc[2][4] = {};

    int sk = tid >> 2, sd = (tid & 3) * 16;
    int vrow = tid >> 2, vcol = (tid & 3) * 16;

    const unsigned short* Ku = (const unsigned short*)(K + base);
    const unsigned short* Vg = (const unsigned short*)Vt_g +
                               (size_t)bh * 64 * SEQ_LEN + (size_t)vrow * SEQ_LEN;

    int t0 = sw.z * (64 / KS);
    int t1 = t0 + 64 / KS;

    // staging registers (single-buffered: load t+1 -> compute t -> store t+1)
    short8v rk0, rk1, rv0, rv1;
    {   // prologue: tile t0 global -> regs -> LDS
        int kt0 = t0 * 64;
        const unsigned short* kp = Ku + (size_t)(kt0 + sk) * QKV_STRIDE + sd;
        rk0 = *(const short8v*)(kp);
        rk1 = *(const short8v*)(kp + 8);
        rv0 = *(const short8v*)(Vg + kt0 + vcol);
        rv1 = *(const short8v*)(Vg + kt0 + vcol + 8);
        *(short8v*)&Ks[sk][sd]     = rk0;
        *(short8v*)&Ks[sk][sd + 8] = rk1;
        *(short8v*)&Vt[vrow][vcol]     = rv0;
        *(short8v*)&Vt[vrow][vcol + 8] = rv1;
    }
    __syncthreads();

    for (int t = t0; t < t1; t++) {
        // T14 issue-early: next tile's global loads go in flight NOW.
        if (t + 1 < t1) {
            int ktn = (t + 1) * 64;
            const unsigned short* kp = Ku + (size_t)(ktn + sk) * QKV_STRIDE + sd;
            rk0 = *(const short8v*)(kp);
            rk1 = *(const short8v*)(kp + 8);
            rv0 = *(const short8v*)(Vg + ktn + vcol);
            rv1 = *(const short8v*)(Vg + ktn + vcol + 8);
        }

        // QK^T: per kt load K frags once, use for both m-tiles
        float4v st[2][4];
        __builtin_amdgcn_s_setprio(1);
#pragma unroll
        for (int kt = 0; kt < 4; kt++) {
            short8v bK0 = *(const short8v*)&Ks[kt * 16 + m][g * 8];
            short8v bK1 = *(const short8v*)&Ks[kt * 16 + m][32 + g * 8];
#pragma unroll
            for (int mt = 0; mt < 2; mt++) {
                float4v a = {0.f, 0.f, 0.f, 0.f};
                a = __builtin_amdgcn_mfma_f32_16x16x32_bf16(bK0, aQ[mt][0], a, 0, 0, 0);
                a = __builtin_amdgcn_mfma_f32_16x16x32_bf16(bK1, aQ[mt][1], a, 0, 0, 0);
                st[mt][kt] = a;
            }
        }
        __builtin_amdgcn_s_setprio(0);

        __syncthreads();   // barrier A: ALL waves' Ks reads done -> Pt may overlay

        // online softmax per m-tile (exp2 domain, defer-max); Pt in Ks overlay
        short8v bP[2][2];
#pragma unroll
        for (int mt = 0; mt < 2; mt++) {
            float u0 = F3(st[mt][0][0], st[mt][0][1], st[mt][0][2]);
            float u1 = F3(st[mt][0][3], st[mt][1][0], st[mt][1][1]);
            float u2 = F3(st[mt][1][2], st[mt][1][3], st[mt][2][0]);
            float u3 = F3(st[mt][2][1], st[mt][2][2], st[mt][2][3]);
            float u4 = F3(st[mt][3][0], st[mt][3][1], st[mt][3][2]);
            float tm = fmaxf(F3(u0, u1, u2), F3(u3, u4, st[mt][3][3]));
            tm = fmaxf(tm, __shfl_xor(tm, 16));
            tm = fmaxf(tm, __shfl_xor(tm, 32));
            // T13 defer-max: only rescale when the max grew by > 8 (exp2 dom).
            if (!__all(tm - mrow[mt] <= 8.f)) {
                float mnew = fmaxf(mrow[mt], tm);
                float alpha = exp2fast(mrow[mt] - mnew);
                mrow[mt] = mnew;
                lrow[mt] *= alpha;
#pragma unroll
                for (int dt = 0; dt < 4; dt++)
#pragma unroll
                    for (int r = 0; r < 4; r++) oacc[mt][dt][r] *= alpha;
            }
            float mcur = mrow[mt];
            float2v ps = {0.f, 0.f};
#pragma unroll
            for (int kt = 0; kt < 4; kt++) {
                float p0 = exp2fast(st[mt][kt][0] - mcur);
                float p1 = exp2fast(st[mt][kt][1] - mcur);
                float p2 = exp2fast(st[mt][kt][2] - mcur);
                float p3 = exp2fast(st[mt][kt][3] - mcur);
                float2v a = {p0, p1}, b = {p2, p3};
                ps += a + b;                       // v_pk_add_f32
                pack_u pp;
                pp.u[0] = cvt_pk_bf16(p0, p1);
                pp.u[1] = cvt_pk_bf16(p2, p3);
                *(short4v*)&PtW[m * 72 + kt * 16 + g * 4] = pp.v4;
            }
            lrow[mt] += ps[0] + ps[1];
            // read back this mt's P^T frags (same wave; lgkmcnt orders it),
            // then the 16-row region is reused by mt=1.
#pragma unroll
            for (int c = 0; c < 2; c++)
                bP[mt][c] = *(const short8v*)&PtW[m * 72 + c * 32 + g * 8];
        }

        // PV: Vt A-frags loaded once, used for both m-tiles
        __builtin_amdgcn_s_setprio(1);
#pragma unroll
        for (int dt = 0; dt < 4; dt++) {
#pragma unroll
            for (int c = 0; c < 2; c++) {
                short8v av = *(const short8v*)&Vt[dt * 16 + m][c * 32 + g * 8];
#pragma unroll
                for (int mt = 0; mt < 2; mt++)
                    oacc[mt][dt] = __builtin_amdgcn_mfma_f32_16x16x32_bf16(av, bP[mt][c], oacc[mt][dt], 0, 0, 0);
            }
        }
        __builtin_amdgcn_s_setprio(0);

        __syncthreads();   // barrier B: PV Vt reads + all Pt reads done
        // T14 write-late: regs (already landed during compute) -> LDS
        if (t + 1 < t1) {
            *(short8v*)&Ks[sk][sd]     = rk0;   // overwrites the Pt overlay
            *(short8v*)&Ks[sk][sd + 8] = rk1;
            *(short8v*)&Vt[vrow][vcol]     = rv0;
            *(short8v*)&Vt[vrow][vcol + 8] = rv1;
        }
        __syncthreads();   // barrier C: staged tile t+1 visible
    }

    size_t zoff = (size_t)sw.z * NUM_HEADS * BATCH + bh;
    size_t pbase = zoff * (SEQ_LEN * (size_t)HEAD_DIM);
#pragma unroll
    for (int mt = 0; mt < 2; mt++) {
        float l = lrow[mt];
        l += __shfl_xor(l, 16);
        l += __shfl_xor(l, 32);
        int q = q0w + mt * 16 + m;
        bf16* orow = Op + pbase + (size_t)q * HEAD_DIM;
#pragma unroll
        for (int dt = 0; dt < 4; dt++) {
            pack_u oo;
            oo.u[0] = cvt_pk_bf16(oacc[mt][dt][0], oacc[mt][dt][1]);
            oo.u[1] = cvt_pk_bf16(oacc[mt][dt][2], oacc[mt][dt][3]);
            *(short4v*)&orow[dt * 16 + g * 4] = oo.v4;
        }
        if (g == 0) mlout[zoff * SEQ_LEN + q] = make_float2(mrow[mt], l);
    }
}

// Merge KS partials -> attention output ab [TOKENS][D_MODEL] (exp2 domain)
template <int KS>
__global__ void attn_merge(const bf16* __restrict__ Op, const float2* __restrict__ ml,
                           bf16* __restrict__ O) {
    int i = blockIdx.x * 256 + threadIdx.x;   // over 16*4096*64
    int d = i & 63;
    int q = (i >> 6) & (SEQ_LEN - 1);
    int bh = i >> 18;
    const int HQ = NUM_HEADS * BATCH * SEQ_LEN;
    float2 a[KS];
    float M = -1e30f;
#pragma unroll
    for (int p = 0; p < KS; p++) {
        a[p] = ml[(size_t)p * HQ + bh * SEQ_LEN + q];
        M = fmaxf(M, a[p].x);
    }
    float w[KS];
    float denom = 0.f;
#pragma unroll
    for (int p = 0; p < KS; p++) {
        w[p] = exp2fast(a[p].x - M);
        denom += a[p].y * w[p];
    }
    float inv = 1.f / denom;
    const size_t NP = (size_t)HQ * HEAD_DIM;
    float o = 0.f;
#pragma unroll
    for (int p = 0; p < KS; p++) o += b2f(Op[(size_t)p * NP + i]) * w[p];
    o *= inv;
    O[((size_t)((bh >> 3) * SEQ_LEN + q)) * D_MODEL + (bh & 7) * HEAD_DIM + d] = f2b(o);
}

// ------------------------------------------------------------------------------
extern "C" void kernel_launch(void* const* d_in, const int* in_sizes, int n_in,
                              void* d_out, int out_size, void* d_ws, size_t ws_size,
                              hipStream_t stream) {
    const void* x     = d_in[0];
    const void* Wq    = d_in[1];
    const void* bq    = d_in[2];
    const void* Wk    = d_in[3];
    const void* bk    = d_in[4];
    const void* Wv    = d_in[5];
    const void* bv    = d_in[6];
    const void* Wo    = d_in[7];
    const void* bo    = d_in[8];
    const void* ln1_g = d_in[9];
    const void* ln1_b = d_in[10];
    const void* ln2_g = d_in[11];
    const void* ln2_b = d_in[12];
    const void* W1    = d_in[13];
    const void* b1    = d_in[14];
    const void* W2    = d_in[15];
    const void* b2    = d_in[16];

    // ---- workspace layout ----
    char* p = (char*)d_ws;
    int* flag = (int*)p;                      p += 256;
    size_t tok_d = (size_t)TOKENS * D_MODEL;
    // region2: KSPLIT bf16 O-partials (16.8 MB) overlay x1b+hb (16.8 MB)
    char* region2 = p;                        p += 2 * tok_d * 2;
    bf16* x1b   = (bf16*)region2;                              // [TOKENS][512]
    bf16* hb    = (bf16*)(region2 + tok_d * 2);                // [TOKENS][512]
    bf16* Opart = (bf16*)region2;
    bf16*  bigA = (bf16*)p;                   p += (size_t)TOKENS * D_FF * 2;  // 33.6 MB
    bf16*  qkvb = bigA;                                   // [TOKENS][1536]
    bf16*  ab   = bigA + (size_t)TOKENS * QKV_STRIDE;     // [TOKENS][512]
    bf16*  ffb  = bigA;                                   // [TOKENS][2048]
    bf16*  Wqkvt = (bf16*)p;                  p += (size_t)QKV_STRIDE * D_MODEL * 2;
    bf16*  Wot   = (bf16*)p;                  p += (size_t)D_MODEL * D_MODEL * 2;  // contiguous
    bf16*  W1t   = (bf16*)p;                  p += (size_t)D_FF * D_MODEL * 2;
    bf16*  W2t   = (bf16*)p;                  p += (size_t)D_MODEL * D_FF * 2;
    bf16*  Vtg   = (bf16*)p;                  p += (size_t)NUM_HEADS * BATCH * HEAD_DIM * SEQ_LEN * 2;
    float2* mlb  = (float2*)p;                p += (size_t)KSPLIT * NUM_HEADS * BATCH * SEQ_LEN * sizeof(float2);
    bf16*  small = (bf16*)p;                  p += 6656 * 2;
    bf16* bias_qkv = small + 0;
    bf16* bias_o   = small + 1536;
    bf16* b1b      = small + 2048;
    bf16* b2b      = small + 4096;
    bf16* g1b      = small + 4608;
    bf16* be1b     = small + 5120;
    bf16* g2b      = small + 5632;
    bf16* be2b     = small + 6144;
    (void)g1b; (void)be1b;

    // fused prep + LN1 (LN1 reads raw x and raw ln1_g/ln1_b; flag via self_detect)
    prep_ln_kernel<<<794 + TOKENS, 256, 0, stream>>>(
        x, Wq, Wk, Wv, Wo, W1, W2, bq, bk, bv, bo, b1, b2,
        ln1_g, ln1_b, ln2_g, ln2_b, Wqkvt, W1t, W2t, small, flag, hb);

    // fused QKV projection (64-col tiles, 1536 blocks = 6/CU);
    // V part written transposed straight into Vtg
    mfma_gemm64<0, 0, 0, 1><<<dim3(QKV_STRIDE / 64, TOKENS / 128), 256, 0, stream>>>(
        hb, Wqkvt, bias_qkv, nullptr, qkvb, Vtg, flag, TOKENS, QKV_STRIDE, D_MODEL);

    flash_attn<KSPLIT><<<dim3(SEQ_LEN / 128, 16, KSPLIT), 256, 0, stream>>>(
        qkvb, qkvb + 512, Vtg, Opart, mlb);
    attn_merge<KSPLIT><<<(NUM_HEADS * BATCH * SEQ_LEN * HEAD_DIM) / 256, 256, 0, stream>>>(
        Opart, mlb, ab);

    // O projection + residual(raw x) -> x1 (bf16); 512 blocks
    mfma_gemm64<0, 3, 0, 0><<<dim3(D_MODEL / 64, TOKENS / 128), 256, 0, stream>>>(
        ab, Wot, bias_o, x, x1b, nullptr, flag, TOKENS, D_MODEL, D_MODEL);

    ln_kernel<0><<<TOKENS, 256, 0, stream>>>(x1b, g2b, be2b, hb, flag);

    // FFN1 + GELU (64-col tiles, 2048 blocks = 6/CU)
    mfma_gemm64<1, 0, 0, 0><<<dim3(D_FF / 64, TOKENS / 128), 256, 0, stream>>>(
        hb, W1t, b1b, nullptr, ffb, nullptr, flag, TOKENS, D_FF, D_MODEL);

    // FFN2 + residual(x1 bf16) -> out (dtype per flag); 512 blocks
    mfma_gemm64<0, 2, 2, 0><<<dim3(D_MODEL / 64, TOKENS / 128), 256, 0, stream>>>(
        ffb, W2t, b2b, x1b, d_out, nullptr, flag, TOKENS, D_MODEL, D_FF);
}